// Round 12
// baseline (371.832 us; speedup 1.0000x reference)
//
#include <hip/hip_runtime.h>
#include <hip/hip_bf16.h>
#include <stdint.h>

// ---------------------------------------------------------------------------
// SelfAttention block: out = (attn(rope(rms(xWq)), rope(rms(xWk)), xWv)) Wo
// B=2, N=2048, D=2048, H=16, HD=128.  All GEMMs + attention in bf16 MFMA.
// ---------------------------------------------------------------------------

typedef __bf16 bf16;
typedef __bf16 bf16x8 __attribute__((ext_vector_type(8)));
typedef __bf16 bf16x4 __attribute__((ext_vector_type(4)));
typedef float  f32x4  __attribute__((ext_vector_type(4)));
typedef float  f32x16 __attribute__((ext_vector_type(16)));
typedef unsigned int uint2v __attribute__((ext_vector_type(2)));

#define MTOT   4096   // B*N token rows
#define DMODEL 2048
#define NSEQ   2048
#define NHEAD  16
#define HDIM   128

static __device__ __forceinline__ void async_ld16(const void* g, void* l) {
  void* gnc = const_cast<void*>(g);
  __builtin_amdgcn_global_load_lds((__attribute__((address_space(1))) void*)gnc,
                                   (__attribute__((address_space(3))) void*)l,
                                   16, 0, 0);
}

static __device__ __forceinline__ float exp2_hw(float x) {
  float r;
  asm("v_exp_f32 %0, %1" : "=v"(r) : "v"(x));
  return r;
}

// ---------------------------------------------------------------------------
// Fused f32 -> bf16 converts: x, wq, wk, wv in one launch.
// ---------------------------------------------------------------------------
#define XG (MTOT * DMODEL / 8)      // 1048576 groups of 8
#define WG (DMODEL * DMODEL / 8)    // 524288

__global__ __launch_bounds__(256) void k_cvt4(
    const float* __restrict__ x, const float* __restrict__ wq,
    const float* __restrict__ wk, const float* __restrict__ wv,
    bf16* __restrict__ xb, bf16* __restrict__ wqb, bf16* __restrict__ wkb,
    bf16* __restrict__ wvb) {
  int stride = gridDim.x * blockDim.x;
  for (int i = blockIdx.x * blockDim.x + threadIdx.x; i < XG + 3 * WG;
       i += stride) {
    const float* src;
    bf16* dst;
    int off;
    if (i < XG) { src = x; dst = xb; off = i; }
    else if (i < XG + WG) { src = wq; dst = wqb; off = i - XG; }
    else if (i < XG + 2 * WG) { src = wk; dst = wkb; off = i - XG - WG; }
    else { src = wv; dst = wvb; off = i - XG - 2 * WG; }
    const float4* p = (const float4*)(src) + 2 * (size_t)off;
    float4 a = p[0], b = p[1];
    bf16x8 o;
    o[0] = (bf16)a.x; o[1] = (bf16)a.y; o[2] = (bf16)a.z; o[3] = (bf16)a.w;
    o[4] = (bf16)b.x; o[5] = (bf16)b.y; o[6] = (bf16)b.z; o[7] = (bf16)b.w;
    *((bf16x8*)(dst) + off) = o;
  }
}

__global__ __launch_bounds__(256) void k_cvt(const float* __restrict__ in,
                                             bf16* __restrict__ out, int n8) {
  int stride = gridDim.x * blockDim.x;
  for (int i = blockIdx.x * blockDim.x + threadIdx.x; i < n8; i += stride) {
    const float4* p = (const float4*)(in) + 2 * (size_t)i;
    float4 a = p[0], b = p[1];
    bf16x8 o;
    o[0] = (bf16)a.x; o[1] = (bf16)a.y; o[2] = (bf16)a.z; o[3] = (bf16)a.w;
    o[4] = (bf16)b.x; o[5] = (bf16)b.y; o[6] = (bf16)b.z; o[7] = (bf16)b.w;
    *((bf16x8*)(out) + i) = o;
  }
}

// ---------------------------------------------------------------------------
// GEMM qk (R10): 256x256 tile, 8 waves, wave tile 128x64, dbuf LDS 128KB,
// counted vmcnt(8), raw s_barrier.  Grid 256 = 1 balanced round.
// ---------------------------------------------------------------------------
__global__ __launch_bounds__(512, 2) void k_gemm_qk(
    const bf16* __restrict__ xb, const bf16* __restrict__ wq,
    const bf16* __restrict__ wk, const float* __restrict__ bq,
    const float* __restrict__ bk, bf16* __restrict__ q, bf16* __restrict__ k) {
  extern __shared__ __align__(16) bf16 dyn[];  // [2][A 16384 + B 16384]

  const int swz = (blockIdx.x & 7) * 32 + (blockIdx.x >> 3);  // XCD-grouped
  const int mt = swz >> 4, nt = swz & 15;
  const int sec = nt >> 3;
  const int m0 = mt * 256, n0 = (nt & 7) * 256;
  const bf16* W = sec ? wk : wq;
  const float* bias = sec ? bk : bq;
  bf16* outp = sec ? k : q;

  const int tid = threadIdx.x;
  const int lane = tid & 63, w = tid >> 6;
  const int wm = w >> 2, wn = w & 3;
  const int g = lane >> 4, r0 = lane & 15;

  f32x4 acc[8][4];
  const f32x4 vzero = {0.f, 0.f, 0.f, 0.f};
#pragma unroll
  for (int i = 0; i < 8; ++i)
#pragma unroll
    for (int j = 0; j < 4; ++j) acc[i][j] = vzero;

  const bf16* Abase = xb + (size_t)m0 * DMODEL;
  const bf16* Wbase = W + (size_t)n0 * DMODEL;

  auto stage = [&](int kt, int buf) {
    const bf16* asrc = Abase + kt * 64;
    const bf16* bsrc = Wbase + kt * 64;
    bf16* sA = dyn + buf * 32768;
    bf16* sB = sA + 16384;
#pragma unroll
    for (int p = 0; p < 4; ++p) {
      int ch = tid + p * 512;
      int row = ch >> 3, c = (ch & 7) ^ (row & 7);
      async_ld16(asrc + (size_t)row * DMODEL + c * 8, sA + ch * 8);
    }
#pragma unroll
    for (int p = 0; p < 4; ++p) {
      int ch = tid + p * 512;
      int row = ch >> 3, c = (ch & 7) ^ (row & 7);
      async_ld16(bsrc + (size_t)row * DMODEL + c * 8, sB + ch * 8);
    }
  };

  const int NT = DMODEL / 64;  // 32
  stage(0, 0);
  for (int kt = 0; kt < NT; ++kt) {
    const int cur = kt & 1;
    if (kt > 0) __builtin_amdgcn_s_barrier();
    if (kt + 1 < NT) {
      stage(kt + 1, cur ^ 1);
      asm volatile("s_waitcnt vmcnt(8)" ::: "memory");
    } else {
      asm volatile("s_waitcnt vmcnt(0)" ::: "memory");
    }
    __builtin_amdgcn_s_barrier();
    const bf16* sA = dyn + cur * 32768;
    const bf16* sB = sA + 16384;

    bf16x8 a0[8], a1[8], b0[4], b1[4];
#pragma unroll
    for (int i = 0; i < 4; ++i) {
      int ra = wm * 128 + i * 16 + r0;
#pragma unroll
      for (int ks = 0; ks < 2; ++ks) {
        int cc = ks * 4 + g;
        a0[i * 2 + ks] = *(const bf16x8*)(sA + ra * 64 + ((cc ^ (ra & 7)) << 3));
      }
    }
#pragma unroll
    for (int j = 0; j < 2; ++j) {
      int rb = wn * 64 + j * 16 + r0;
#pragma unroll
      for (int ks = 0; ks < 2; ++ks) {
        int cc = ks * 4 + g;
        b0[j * 2 + ks] = *(const bf16x8*)(sB + rb * 64 + ((cc ^ (rb & 7)) << 3));
      }
    }
#pragma unroll
    for (int j = 0; j < 2; ++j) {
      int rb = wn * 64 + 32 + j * 16 + r0;
#pragma unroll
      for (int ks = 0; ks < 2; ++ks) {
        int cc = ks * 4 + g;
        b1[j * 2 + ks] = *(const bf16x8*)(sB + rb * 64 + ((cc ^ (rb & 7)) << 3));
      }
    }
    __builtin_amdgcn_s_setprio(1);
#pragma unroll
    for (int i = 0; i < 4; ++i)
#pragma unroll
      for (int j = 0; j < 2; ++j)
#pragma unroll
        for (int ks = 0; ks < 2; ++ks)
          acc[i][j] = __builtin_amdgcn_mfma_f32_16x16x32_bf16(
              a0[i * 2 + ks], b0[j * 2 + ks], acc[i][j], 0, 0, 0);
    __builtin_amdgcn_s_setprio(0);
#pragma unroll
    for (int i = 0; i < 4; ++i) {
      int ra = wm * 128 + 64 + i * 16 + r0;
#pragma unroll
      for (int ks = 0; ks < 2; ++ks) {
        int cc = ks * 4 + g;
        a1[i * 2 + ks] = *(const bf16x8*)(sA + ra * 64 + ((cc ^ (ra & 7)) << 3));
      }
    }
    __builtin_amdgcn_s_setprio(1);
#pragma unroll
    for (int i = 0; i < 4; ++i)
#pragma unroll
      for (int j = 0; j < 2; ++j)
#pragma unroll
        for (int ks = 0; ks < 2; ++ks)
          acc[i][2 + j] = __builtin_amdgcn_mfma_f32_16x16x32_bf16(
              a0[i * 2 + ks], b1[j * 2 + ks], acc[i][2 + j], 0, 0, 0);
    __builtin_amdgcn_s_setprio(0);
    __builtin_amdgcn_s_setprio(1);
#pragma unroll
    for (int i = 0; i < 4; ++i)
#pragma unroll
      for (int j = 0; j < 2; ++j)
#pragma unroll
        for (int ks = 0; ks < 2; ++ks)
          acc[4 + i][j] = __builtin_amdgcn_mfma_f32_16x16x32_bf16(
              a1[i * 2 + ks], b0[j * 2 + ks], acc[4 + i][j], 0, 0, 0);
    __builtin_amdgcn_s_setprio(0);
    __builtin_amdgcn_s_setprio(1);
#pragma unroll
    for (int i = 0; i < 4; ++i)
#pragma unroll
      for (int j = 0; j < 2; ++j)
#pragma unroll
        for (int ks = 0; ks < 2; ++ks)
          acc[4 + i][2 + j] = __builtin_amdgcn_mfma_f32_16x16x32_bf16(
              a1[i * 2 + ks], b1[j * 2 + ks], acc[4 + i][2 + j], 0, 0, 0);
    __builtin_amdgcn_s_setprio(0);
  }

#pragma unroll
  for (int i = 0; i < 8; ++i) {
#pragma unroll
    for (int j = 0; j < 4; ++j) {
      int mb = m0 + wm * 128 + (i >> 2) * 64 + (i & 3) * 16 + g * 4;
      int n = n0 + wn * 64 + (j >> 1) * 32 + (j & 1) * 16 + r0;
      float bn = bias[n];
#pragma unroll
      for (int r = 0; r < 4; ++r)
        outp[(size_t)(mb + r) * DMODEL + n] = (bf16)(acc[i][j][r] + bn);
    }
  }
}

// ---------------------------------------------------------------------------
// GEMM v3 (R4 structure): 128x256 tile, triple-buffered LDS, counted
// vmcnt(6), raw s_barrier.  For v-projection (transposed) and out-projection.
// ---------------------------------------------------------------------------
#define BUFELEMS (384 * 64)   // 48KB per buffer (A 128x64 + B 256x64)

template <int OUTMODE>
static __device__ __forceinline__ void gemm256_body(
    const bf16* __restrict__ A, const bf16* __restrict__ W,
    const float* __restrict__ bias, void* __restrict__ outp, int m0, int n0) {
  extern __shared__ __align__(16) bf16 dynls[];

  const int tid = threadIdx.x;
  const int lane = tid & 63, w = tid >> 6;
  const int wm = w >> 2, wn = w & 3;
  const int g = lane >> 4, r0 = lane & 15;

  f32x4 acc[4][4];
  const f32x4 vzero = {0.f, 0.f, 0.f, 0.f};
#pragma unroll
  for (int i = 0; i < 4; ++i)
#pragma unroll
    for (int j = 0; j < 4; ++j) acc[i][j] = vzero;

  const bf16* Abase = A + (size_t)m0 * DMODEL;
  const bf16* Wbase = W + (size_t)n0 * DMODEL;

  auto stage_a = [&](int kt, int buf) {
    const bf16* asrc = Abase + kt * 64;
    const bf16* bsrc = Wbase + kt * 64;
    bf16* sBuf = dynls + buf * BUFELEMS;
#pragma unroll
    for (int p = 0; p < 2; ++p) {
      int ch = tid + p * 512;
      int row = ch >> 3, c = (ch & 7) ^ (row & 7);
      async_ld16(asrc + (size_t)row * DMODEL + c * 8, sBuf + ch * 8);
    }
    {
      int ch = tid;
      int row = ch >> 3, c = (ch & 7) ^ (row & 7);
      async_ld16(bsrc + (size_t)row * DMODEL + c * 8, sBuf + 128 * 64 + ch * 8);
    }
  };
  auto stage_b = [&](int kt, int buf) {
    const bf16* bsrc = Wbase + kt * 64;
    bf16* sBuf = dynls + buf * BUFELEMS + 128 * 64;
#pragma unroll
    for (int p = 1; p < 4; ++p) {
      int ch = tid + p * 512;
      int row = ch >> 3, c = (ch & 7) ^ (row & 7);
      async_ld16(bsrc + (size_t)row * DMODEL + c * 8, sBuf + ch * 8);
    }
  };

  const int NT = DMODEL / 64;  // 32
  stage_a(0, 0); stage_b(0, 0);
  stage_a(1, 1); stage_b(1, 1);
  asm volatile("s_waitcnt vmcnt(6)" ::: "memory");
  __builtin_amdgcn_s_barrier();

  for (int kt = 0; kt < NT; ++kt) {
    const bf16* sA = dynls + (kt % 3) * BUFELEMS;
    const bf16* sB = sA + 128 * 64;
    const bool pf = (kt + 2) < NT;
    const int nb = (kt + 2) % 3;

#pragma unroll
    for (int ks = 0; ks < 2; ++ks) {
      bf16x8 af[4], bfr[4];
      const int cc = ks * 4 + g;
#pragma unroll
      for (int i = 0; i < 4; ++i) {
        int ra = wm * 64 + i * 16 + r0;
        af[i] = *(const bf16x8*)(sA + ra * 64 + ((cc ^ (ra & 7)) << 3));
        int rb = wn * 64 + i * 16 + r0;
        bfr[i] = *(const bf16x8*)(sB + rb * 64 + ((cc ^ (rb & 7)) << 3));
      }
      if (ks == 0) {
        if (pf) stage_a(kt + 2, nb);
      } else {
        if (pf) {
          stage_b(kt + 2, nb);
          asm volatile("s_waitcnt vmcnt(6)" ::: "memory");
        } else {
          asm volatile("s_waitcnt vmcnt(0)" ::: "memory");
        }
      }
      __builtin_amdgcn_sched_barrier(0);
      __builtin_amdgcn_s_barrier();
      __builtin_amdgcn_sched_barrier(0);
      __builtin_amdgcn_s_setprio(1);
#pragma unroll
      for (int i = 0; i < 4; ++i)
#pragma unroll
        for (int j = 0; j < 4; ++j)
          acc[i][j] = __builtin_amdgcn_mfma_f32_16x16x32_bf16(af[i], bfr[j],
                                                              acc[i][j], 0, 0, 0);
      __builtin_amdgcn_s_setprio(0);
    }
  }

#pragma unroll
  for (int i = 0; i < 4; ++i) {
#pragma unroll
    for (int j = 0; j < 4; ++j) {
      int mb = m0 + wm * 64 + i * 16 + g * 4;
      int n = n0 + wn * 64 + j * 16 + r0;
      float bn = bias[n];
      if (OUTMODE == 2) {
        float* o = (float*)outp;
#pragma unroll
        for (int r = 0; r < 4; ++r)
          o[(size_t)(mb + r) * DMODEL + n] = acc[i][j][r] + bn;
      } else {
        bf16* o = (bf16*)outp;
        int bb = mb >> 11, s = mb & (NSEQ - 1);
        bf16x4 pk;
#pragma unroll
        for (int r = 0; r < 4; ++r) pk[r] = (bf16)(acc[i][j][r] + bn);
        *(bf16x4*)(o + (size_t)(bb * DMODEL + n) * NSEQ + s) = pk;
      }
    }
  }
}

__global__ __launch_bounds__(512, 2) void k_gemm_v(
    const bf16* __restrict__ xb, const bf16* __restrict__ wv,
    const float* __restrict__ bv, bf16* __restrict__ vt) {
  gemm256_body<1>(xb, wv, bv, vt, blockIdx.y * 128, blockIdx.x * 256);
}

__global__ __launch_bounds__(512, 2) void k_gemm_out(
    const bf16* __restrict__ ab, const bf16* __restrict__ wo,
    const float* __restrict__ bo, float* __restrict__ out) {
  gemm256_body<2>(ab, wo, bo, out, blockIdx.y * 128, blockIdx.x * 256);
}

// ---------------------------------------------------------------------------
// Fused RMSNorm + RoPE.  Q pre-scaled by (1/sqrt(HD)) * log2(e) so attention
// softmax runs natively in the exp2 domain.
// ---------------------------------------------------------------------------
__global__ __launch_bounds__(256) void k_norm_rope(
    bf16* __restrict__ q, bf16* __restrict__ kk, const float* __restrict__ gq,
    const float* __restrict__ gk, const float* __restrict__ freqs) {
  int bidx = blockIdx.x;
  bf16* buf = (bidx < MTOT) ? q : kk;
  const float* gw = (bidx < MTOT) ? gq : gk;
  float qs = (bidx < MTOT) ? (0.08838834764831845f * 1.4426950408889634f)
                           : 1.0f;
  int row = bidx & (MTOT - 1);
  int s = row & (NSEQ - 1);
  int tid = threadIdx.x;
  int i0 = tid * 8;
  bf16* ptr = buf + (size_t)row * DMODEL + i0;
  bf16x8 v = *(const bf16x8*)ptr;
  float x[8];
  float ssq = 0.f;
#pragma unroll
  for (int j = 0; j < 8; ++j) {
    x[j] = (float)v[j];
    ssq += x[j] * x[j];
  }
#pragma unroll
  for (int off = 1; off < 64; off <<= 1) ssq += __shfl_xor(ssq, off);
  __shared__ float part[4];
  if ((tid & 63) == 0) part[tid >> 6] = ssq;
  __syncthreads();
  float tot = part[0] + part[1] + part[2] + part[3];
  float sc = rsqrtf(tot * (1.f / DMODEL) + 1e-6f) * qs;
  float4 g0 = *(const float4*)(gw + i0);
  float4 g1 = *(const float4*)(gw + i0 + 4);
  float y[8];
  y[0] = x[0] * sc * g0.x; y[1] = x[1] * sc * g0.y;
  y[2] = x[2] * sc * g0.z; y[3] = x[3] * sc * g0.w;
  y[4] = x[4] * sc * g1.x; y[5] = x[5] * sc * g1.y;
  y[6] = x[6] * sc * g1.z; y[7] = x[7] * sc * g1.w;
  int dl = i0 & (HDIM - 1);
  const float* fp = freqs + (size_t)s * HDIM + dl;
  float4 f0 = *(const float4*)fp;
  float4 f1 = *(const float4*)(fp + 4);
  bf16x8 out;
  out[0] = (bf16)(y[0] * f0.x - y[1] * f0.y);
  out[1] = (bf16)(y[0] * f0.y + y[1] * f0.x);
  out[2] = (bf16)(y[2] * f0.z - y[3] * f0.w);
  out[3] = (bf16)(y[2] * f0.w + y[3] * f0.z);
  out[4] = (bf16)(y[4] * f1.x - y[5] * f1.y);
  out[5] = (bf16)(y[4] * f1.y + y[5] * f1.x);
  out[6] = (bf16)(y[6] * f1.z - y[7] * f1.w);
  out[7] = (bf16)(y[6] * f1.w + y[7] * f1.z);
  *(bf16x8*)ptr = out;
}

// ---------------------------------------------------------------------------
// Flash attention v7: R10 algebra with KVBLK=32 -> LDS 32KB -> 4 blocks/CU
// (16 waves/CU, double the TLP).  Single s-slice per tile; V stored as 32
// quad-rows (d, d+32, d+64, d+96 share a 256B LDS row) keeping the 4-bit XOR
// swizzle that measured 0 bank conflicts.  64 KV-tiles of 32 keys each.
// ---------------------------------------------------------------------------
#define LOG2E_THR 11.541560327111707f  // 8 * log2(e)
#define KVB 32

__global__ __launch_bounds__(256, 4) void k_attn(const bf16* __restrict__ q,
                                                 const bf16* __restrict__ k,
                                                 const bf16* __restrict__ vt,
                                                 bf16* __restrict__ o) {
  __shared__ __align__(16) bf16 sk[2][KVB * 128];   // 8KB per buf
  __shared__ __align__(16) bf16 sv[2][KVB * 128];   // 32 quad-rows x 256B
  const int bid = blockIdx.x;
  const int idx = bid >> 3;
  const int bh = (bid & 7) * 4 + (idx >> 4);  // 4 bh per XCD
  const int qt = idx & 15;
  const int bb = bh >> 4, h = bh & 15;
  const int tid = threadIdx.x;
  const int lane = tid & 63, w = tid >> 6;
  const int l31 = lane & 31, b5 = lane >> 5;

  // Q fragments (pre-scaled by log2e/sqrt(HD)): qf[kk] = Q[q0+l31][16kk+8b5+j]
  bf16x8 qf[8];
  {
    const bf16* qb =
        q + (size_t)(bb * NSEQ + qt * 128 + w * 32 + l31) * DMODEL + h * HDIM +
        b5 * 8;
#pragma unroll
    for (int kk = 0; kk < 8; ++kk) qf[kk] = *(const bf16x8*)(qb + kk * 16);
  }

  f32x16 oacc[4];
#pragma unroll
  for (int dt = 0; dt < 4; ++dt)
#pragma unroll
    for (int r = 0; r < 16; ++r) oacc[dt][r] = 0.f;
  f32x16 sum_acc;
#pragma unroll
  for (int r = 0; r < 16; ++r) sum_acc[r] = 0.f;
  float m = 0.f;  // log2 domain

  union { uint32_t u[4]; bf16x8 v; } ones;
  ones.u[0] = ones.u[1] = ones.u[2] = ones.u[3] = 0x3F803F80u;  // 1.0 bf16 x2

  const bf16* kbase = k + (size_t)(bb * NSEQ) * DMODEL + h * HDIM;
  const bf16* vbase = vt + (size_t)(bb * DMODEL + h * HDIM) * NSEQ;

  auto stage = [&](int t, int buf) {
    int k0 = t * KVB;
#pragma unroll
    for (int p = 0; p < 2; ++p) {  // K: 32 rows x 16 chunks, swizzle row&15
      int ch = tid + p * 256;
      int row = ch >> 4, cs = ch & 15;
      int c = cs ^ (row & 15);
      async_ld16(kbase + (size_t)(k0 + row) * DMODEL + c * 8, &sk[buf][ch * 8]);
    }
#pragma unroll
    for (int p = 0; p < 2; ++p) {  // V: 32 quad-rows x 16 chunk-positions
      int ch = tid + p * 256;
      int r2 = ch >> 4, pos = ch & 15;
      int idxv = pos ^ (r2 & 15);
      int d = ((idxv >> 2) << 5) | r2;  // d-row 0..127
      int creal = idxv & 3;             // 8-elem chunk within 32 keys
      async_ld16(vbase + (size_t)d * NSEQ + k0 + creal * 8, &sv[buf][ch * 8]);
    }
  };

  stage(0, 0);
  for (int t = 0; t < NSEQ / KVB; ++t) {
    const int cur = t & 1;
    asm volatile("s_waitcnt vmcnt(0)" ::: "memory");
    __syncthreads();
    if (t + 1 < NSEQ / KVB) stage(t + 1, cur ^ 1);  // overlaps compute

    // S - m = K Q^T with C initialized to -m (log2 domain)
    f32x16 sacc;
#pragma unroll
    for (int r = 0; r < 16; ++r) sacc[r] = -m;
    __builtin_amdgcn_s_setprio(1);
#pragma unroll
    for (int kk = 0; kk < 8; ++kk) {
      const int c = 2 * kk + b5;
      bf16x8 kf = *(const bf16x8*)(&sk[cur][l31 * 128 + ((c ^ (l31 & 15)) << 3)]);
      sacc = __builtin_amdgcn_mfma_f32_32x32x16_bf16(kf, qf[kk], sacc, 0, 0, 0);
    }
    __builtin_amdgcn_s_setprio(0);

    // lane-local max for q = l31 (values are S - m); max3-friendly shape
    float t1[8];
#pragma unroll
    for (int i = 0; i < 8; ++i) t1[i] = fmaxf(sacc[2 * i], sacc[2 * i + 1]);
    float pm = fmaxf(fmaxf(t1[0], t1[1]), t1[2]);
    pm = fmaxf(fmaxf(pm, t1[3]), t1[4]);
    pm = fmaxf(fmaxf(pm, t1[5]), t1[6]);
    pm = fmaxf(pm, t1[7]);
    {
      uint2v r2 = __builtin_amdgcn_permlane32_swap(__float_as_uint(pm),
                                                   __float_as_uint(pm), false,
                                                   false);
      pm = fmaxf(__uint_as_float(r2.x), __uint_as_float(r2.y));
    }
    if (__any(pm > LOG2E_THR)) {  // defer-max (T13)
      float d = fmaxf(pm, 0.f);
      m += d;
      float alpha = exp2_hw(-d);
#pragma unroll
      for (int r = 0; r < 16; ++r) sum_acc[r] *= alpha;
#pragma unroll
      for (int dt = 0; dt < 4; ++dt)
#pragma unroll
        for (int r = 0; r < 16; ++r) oacc[dt][r] *= alpha;
#pragma unroll
      for (int r = 0; r < 16; ++r) sacc[r] -= d;
    }

    // P = exp2(S - m); pack to bf16 pairs
#pragma unroll
    for (int r = 0; r < 16; ++r) sacc[r] = exp2_hw(sacc[r]);
    uint32_t P2[8];
#pragma unroll
    for (int i = 0; i < 8; ++i)
      asm("v_cvt_pk_bf16_f32 %0, %1, %2"
          : "=v"(P2[i])
          : "v"(sacc[2 * i]), "v"(sacc[2 * i + 1]));

    // O^T += V^T P^T ; sum_acc += ones * P^T
    __builtin_amdgcn_s_setprio(1);
#pragma unroll
    for (int u = 0; u < 2; ++u) {
      union { uint32_t uw[4]; bf16x8 v; } pb;
      uint2v ra = __builtin_amdgcn_permlane32_swap(P2[4 * u], P2[4 * u + 2],
                                                   false, false);
      uint2v rb = __builtin_amdgcn_permlane32_swap(P2[4 * u + 1],
                                                   P2[4 * u + 3], false, false);
      pb.uw[0] = ra.x;
      pb.uw[1] = rb.x;
      pb.uw[2] = ra.y;
      pb.uw[3] = rb.y;
      const int c = 2 * u + b5;  // 8-key slice index within 32 keys
      sum_acc = __builtin_amdgcn_mfma_f32_32x32x16_bf16(ones.v, pb.v, sum_acc,
                                                        0, 0, 0);
#pragma unroll
      for (int dt = 0; dt < 4; ++dt) {
        const int pos = ((dt << 2) | c) ^ (l31 & 15);
        bf16x8 vf = *(const bf16x8*)(&sv[cur][l31 * 128 + pos * 8]);
        oacc[dt] = __builtin_amdgcn_mfma_f32_32x32x16_bf16(vf, pb.v, oacc[dt],
                                                           0, 0, 0);
      }
    }
    __builtin_amdgcn_s_setprio(0);
  }

  // epilogue: O[q=l31][d = 32dt + 8rg + 4b5 + e]; l = sum_acc[0]
  const float rl = 1.f / sum_acc[0];
  bf16* ob = o + (size_t)(bb * NSEQ + qt * 128 + w * 32 + l31) * DMODEL +
             h * HDIM;
#pragma unroll
  for (int dt = 0; dt < 4; ++dt) {
#pragma unroll
    for (int rg = 0; rg < 4; ++rg) {
      bf16x4 pk4;
#pragma unroll
      for (int e = 0; e < 4; ++e) pk4[e] = (bf16)(oacc[dt][rg * 4 + e] * rl);
      *(bf16x4*)(ob + dt * 32 + rg * 8 + b5 * 4) = pk4;
    }
  }
}

// ---------------------------------------------------------------------------
extern "C" void kernel_launch(void* const* d_in, const int* in_sizes, int n_in,
                              void* d_out, int out_size, void* d_ws,
                              size_t ws_size, hipStream_t stream) {
  (void)in_sizes; (void)n_in; (void)out_size; (void)ws_size;
  const float* x = (const float*)d_in[0];
  const float* freqs = (const float*)d_in[1];
  const float* wq = (const float*)d_in[2];
  const float* bq = (const float*)d_in[3];
  const float* wk = (const float*)d_in[4];
  const float* bk = (const float*)d_in[5];
  const float* wv = (const float*)d_in[6];
  const float* bv = (const float*)d_in[7];
  const float* wo = (const float*)d_in[8];
  const float* bo = (const float*)d_in[9];
  const float* gq = (const float*)d_in[10];
  const float* gk = (const float*)d_in[11];

  char* ws = (char*)d_ws;
  const size_t SZ_TOK = (size_t)MTOT * DMODEL * sizeof(bf16);
  const size_t SZ_W = (size_t)DMODEL * DMODEL * sizeof(bf16);
  bf16* xb = (bf16*)ws;                 // attn-out after qkv
  bf16* qb = (bf16*)(ws + SZ_TOK);
  bf16* kb = (bf16*)(ws + 2 * SZ_TOK);
  bf16* vtb = (bf16*)(ws + 3 * SZ_TOK);
  bf16* wqb = (bf16*)(ws + 4 * SZ_TOK);  // wo-bf16 after qk
  bf16* wkb = (bf16*)(ws + 4 * SZ_TOK + SZ_W);
  bf16* wvb = (bf16*)(ws + 4 * SZ_TOK + 2 * SZ_W);

  const int LDSB = 3 * BUFELEMS * (int)sizeof(bf16);  // 147456
  const int LDSQK = 2 * 32768 * (int)sizeof(bf16);    // 131072
  hipFuncSetAttribute((const void*)k_gemm_qk,
                      hipFuncAttributeMaxDynamicSharedMemorySize, LDSQK);
  hipFuncSetAttribute((const void*)k_gemm_v,
                      hipFuncAttributeMaxDynamicSharedMemorySize, LDSB);
  hipFuncSetAttribute((const void*)k_gemm_out,
                      hipFuncAttributeMaxDynamicSharedMemorySize, LDSB);

  k_cvt4<<<2048, 256, 0, stream>>>(x, wq, wk, wv, xb, wqb, wkb, wvb);

  k_gemm_qk<<<256, 512, LDSQK, stream>>>(xb, wqb, wkb, bq, bk, qb, kb);
  k_gemm_v<<<dim3(8, 32), 512, LDSB, stream>>>(xb, wvb, bv, vtb);

  k_cvt<<<1024, 256, 0, stream>>>(wo, wqb, (DMODEL * DMODEL) / 8);

  k_norm_rope<<<2 * MTOT, 256, 0, stream>>>(qb, kb, gq, gk, freqs);

  k_attn<<<512, 256, 0, stream>>>(qb, kb, vtb, xb);

  k_gemm_out<<<dim3(8, 32), 512, LDSB, stream>>>(xb, wqb, bo, (float*)d_out);
}

// Round 13
// 266.444 us; speedup vs baseline: 1.3955x; 1.3955x over previous
//
#include <hip/hip_runtime.h>
#include <hip/hip_bf16.h>
#include <stdint.h>

// ---------------------------------------------------------------------------
// SelfAttention block: out = (attn(rope(rms(xWq)), rope(rms(xWk)), xWv)) Wo
// B=2, N=2048, D=2048, H=16, HD=128.  All GEMMs + attention in bf16 MFMA.
// ---------------------------------------------------------------------------

typedef __bf16 bf16;
typedef __bf16 bf16x8 __attribute__((ext_vector_type(8)));
typedef __bf16 bf16x4 __attribute__((ext_vector_type(4)));
typedef float  f32x4  __attribute__((ext_vector_type(4)));
typedef float  f32x16 __attribute__((ext_vector_type(16)));
typedef unsigned int uint2v __attribute__((ext_vector_type(2)));

#define MTOT   4096   // B*N token rows
#define DMODEL 2048
#define NSEQ   2048
#define NHEAD  16
#define HDIM   128

static __device__ __forceinline__ void async_ld16(const void* g, void* l) {
  void* gnc = const_cast<void*>(g);
  __builtin_amdgcn_global_load_lds((__attribute__((address_space(1))) void*)gnc,
                                   (__attribute__((address_space(3))) void*)l,
                                   16, 0, 0);
}

static __device__ __forceinline__ float exp2_hw(float x) {
  float r;
  asm("v_exp_f32 %0, %1" : "=v"(r) : "v"(x));
  return r;
}

// ---------------------------------------------------------------------------
// Fused f32 -> bf16 converts: x, wq, wk, wv in one launch.
// ---------------------------------------------------------------------------
#define XG (MTOT * DMODEL / 8)      // 1048576 groups of 8
#define WG (DMODEL * DMODEL / 8)    // 524288

__global__ __launch_bounds__(256) void k_cvt4(
    const float* __restrict__ x, const float* __restrict__ wq,
    const float* __restrict__ wk, const float* __restrict__ wv,
    bf16* __restrict__ xb, bf16* __restrict__ wqb, bf16* __restrict__ wkb,
    bf16* __restrict__ wvb) {
  int stride = gridDim.x * blockDim.x;
  for (int i = blockIdx.x * blockDim.x + threadIdx.x; i < XG + 3 * WG;
       i += stride) {
    const float* src;
    bf16* dst;
    int off;
    if (i < XG) { src = x; dst = xb; off = i; }
    else if (i < XG + WG) { src = wq; dst = wqb; off = i - XG; }
    else if (i < XG + 2 * WG) { src = wk; dst = wkb; off = i - XG - WG; }
    else { src = wv; dst = wvb; off = i - XG - 2 * WG; }
    const float4* p = (const float4*)(src) + 2 * (size_t)off;
    float4 a = p[0], b = p[1];
    bf16x8 o;
    o[0] = (bf16)a.x; o[1] = (bf16)a.y; o[2] = (bf16)a.z; o[3] = (bf16)a.w;
    o[4] = (bf16)b.x; o[5] = (bf16)b.y; o[6] = (bf16)b.z; o[7] = (bf16)b.w;
    *((bf16x8*)(dst) + off) = o;
  }
}

__global__ __launch_bounds__(256) void k_cvt(const float* __restrict__ in,
                                             bf16* __restrict__ out, int n8) {
  int stride = gridDim.x * blockDim.x;
  for (int i = blockIdx.x * blockDim.x + threadIdx.x; i < n8; i += stride) {
    const float4* p = (const float4*)(in) + 2 * (size_t)i;
    float4 a = p[0], b = p[1];
    bf16x8 o;
    o[0] = (bf16)a.x; o[1] = (bf16)a.y; o[2] = (bf16)a.z; o[3] = (bf16)a.w;
    o[4] = (bf16)b.x; o[5] = (bf16)b.y; o[6] = (bf16)b.z; o[7] = (bf16)b.w;
    *((bf16x8*)(out) + i) = o;
  }
}

// ---------------------------------------------------------------------------
// GEMM qk (R10): 256x256 tile, 8 waves, wave tile 128x64, dbuf LDS 128KB,
// counted vmcnt(8), raw s_barrier.  Grid 256 = 1 balanced round.
// ---------------------------------------------------------------------------
__global__ __launch_bounds__(512, 2) void k_gemm_qk(
    const bf16* __restrict__ xb, const bf16* __restrict__ wq,
    const bf16* __restrict__ wk, const float* __restrict__ bq,
    const float* __restrict__ bk, bf16* __restrict__ q, bf16* __restrict__ k) {
  extern __shared__ __align__(16) bf16 dyn[];  // [2][A 16384 + B 16384]

  const int swz = (blockIdx.x & 7) * 32 + (blockIdx.x >> 3);  // XCD-grouped
  const int mt = swz >> 4, nt = swz & 15;
  const int sec = nt >> 3;
  const int m0 = mt * 256, n0 = (nt & 7) * 256;
  const bf16* W = sec ? wk : wq;
  const float* bias = sec ? bk : bq;
  bf16* outp = sec ? k : q;

  const int tid = threadIdx.x;
  const int lane = tid & 63, w = tid >> 6;
  const int wm = w >> 2, wn = w & 3;
  const int g = lane >> 4, r0 = lane & 15;

  f32x4 acc[8][4];
  const f32x4 vzero = {0.f, 0.f, 0.f, 0.f};
#pragma unroll
  for (int i = 0; i < 8; ++i)
#pragma unroll
    for (int j = 0; j < 4; ++j) acc[i][j] = vzero;

  const bf16* Abase = xb + (size_t)m0 * DMODEL;
  const bf16* Wbase = W + (size_t)n0 * DMODEL;

  auto stage = [&](int kt, int buf) {
    const bf16* asrc = Abase + kt * 64;
    const bf16* bsrc = Wbase + kt * 64;
    bf16* sA = dyn + buf * 32768;
    bf16* sB = sA + 16384;
#pragma unroll
    for (int p = 0; p < 4; ++p) {
      int ch = tid + p * 512;
      int row = ch >> 3, c = (ch & 7) ^ (row & 7);
      async_ld16(asrc + (size_t)row * DMODEL + c * 8, sA + ch * 8);
    }
#pragma unroll
    for (int p = 0; p < 4; ++p) {
      int ch = tid + p * 512;
      int row = ch >> 3, c = (ch & 7) ^ (row & 7);
      async_ld16(bsrc + (size_t)row * DMODEL + c * 8, sB + ch * 8);
    }
  };

  const int NT = DMODEL / 64;  // 32
  stage(0, 0);
  for (int kt = 0; kt < NT; ++kt) {
    const int cur = kt & 1;
    if (kt > 0) __builtin_amdgcn_s_barrier();
    if (kt + 1 < NT) {
      stage(kt + 1, cur ^ 1);
      asm volatile("s_waitcnt vmcnt(8)" ::: "memory");
    } else {
      asm volatile("s_waitcnt vmcnt(0)" ::: "memory");
    }
    __builtin_amdgcn_s_barrier();
    const bf16* sA = dyn + cur * 32768;
    const bf16* sB = sA + 16384;

    bf16x8 a0[8], a1[8], b0[4], b1[4];
#pragma unroll
    for (int i = 0; i < 4; ++i) {
      int ra = wm * 128 + i * 16 + r0;
#pragma unroll
      for (int ks = 0; ks < 2; ++ks) {
        int cc = ks * 4 + g;
        a0[i * 2 + ks] = *(const bf16x8*)(sA + ra * 64 + ((cc ^ (ra & 7)) << 3));
      }
    }
#pragma unroll
    for (int j = 0; j < 2; ++j) {
      int rb = wn * 64 + j * 16 + r0;
#pragma unroll
      for (int ks = 0; ks < 2; ++ks) {
        int cc = ks * 4 + g;
        b0[j * 2 + ks] = *(const bf16x8*)(sB + rb * 64 + ((cc ^ (rb & 7)) << 3));
      }
    }
#pragma unroll
    for (int j = 0; j < 2; ++j) {
      int rb = wn * 64 + 32 + j * 16 + r0;
#pragma unroll
      for (int ks = 0; ks < 2; ++ks) {
        int cc = ks * 4 + g;
        b1[j * 2 + ks] = *(const bf16x8*)(sB + rb * 64 + ((cc ^ (rb & 7)) << 3));
      }
    }
    __builtin_amdgcn_s_setprio(1);
#pragma unroll
    for (int i = 0; i < 4; ++i)
#pragma unroll
      for (int j = 0; j < 2; ++j)
#pragma unroll
        for (int ks = 0; ks < 2; ++ks)
          acc[i][j] = __builtin_amdgcn_mfma_f32_16x16x32_bf16(
              a0[i * 2 + ks], b0[j * 2 + ks], acc[i][j], 0, 0, 0);
    __builtin_amdgcn_s_setprio(0);
#pragma unroll
    for (int i = 0; i < 4; ++i) {
      int ra = wm * 128 + 64 + i * 16 + r0;
#pragma unroll
      for (int ks = 0; ks < 2; ++ks) {
        int cc = ks * 4 + g;
        a1[i * 2 + ks] = *(const bf16x8*)(sA + ra * 64 + ((cc ^ (ra & 7)) << 3));
      }
    }
    __builtin_amdgcn_s_setprio(1);
#pragma unroll
    for (int i = 0; i < 4; ++i)
#pragma unroll
      for (int j = 0; j < 2; ++j)
#pragma unroll
        for (int ks = 0; ks < 2; ++ks)
          acc[i][2 + j] = __builtin_amdgcn_mfma_f32_16x16x32_bf16(
              a0[i * 2 + ks], b1[j * 2 + ks], acc[i][2 + j], 0, 0, 0);
    __builtin_amdgcn_s_setprio(0);
    __builtin_amdgcn_s_setprio(1);
#pragma unroll
    for (int i = 0; i < 4; ++i)
#pragma unroll
      for (int j = 0; j < 2; ++j)
#pragma unroll
        for (int ks = 0; ks < 2; ++ks)
          acc[4 + i][j] = __builtin_amdgcn_mfma_f32_16x16x32_bf16(
              a1[i * 2 + ks], b0[j * 2 + ks], acc[4 + i][j], 0, 0, 0);
    __builtin_amdgcn_s_setprio(0);
    __builtin_amdgcn_s_setprio(1);
#pragma unroll
    for (int i = 0; i < 4; ++i)
#pragma unroll
      for (int j = 0; j < 2; ++j)
#pragma unroll
        for (int ks = 0; ks < 2; ++ks)
          acc[4 + i][2 + j] = __builtin_amdgcn_mfma_f32_16x16x32_bf16(
              a1[i * 2 + ks], b1[j * 2 + ks], acc[4 + i][2 + j], 0, 0, 0);
    __builtin_amdgcn_s_setprio(0);
  }

#pragma unroll
  for (int i = 0; i < 8; ++i) {
#pragma unroll
    for (int j = 0; j < 4; ++j) {
      int mb = m0 + wm * 128 + (i >> 2) * 64 + (i & 3) * 16 + g * 4;
      int n = n0 + wn * 64 + (j >> 1) * 32 + (j & 1) * 16 + r0;
      float bn = bias[n];
#pragma unroll
      for (int r = 0; r < 4; ++r)
        outp[(size_t)(mb + r) * DMODEL + n] = (bf16)(acc[i][j][r] + bn);
    }
  }
}

// ---------------------------------------------------------------------------
// GEMM v3 (R4 structure): 128x256 tile, triple-buffered LDS, counted
// vmcnt(6), raw s_barrier.  For v-projection (transposed) and out-projection.
// ---------------------------------------------------------------------------
#define BUFELEMS (384 * 64)   // 48KB per buffer (A 128x64 + B 256x64)

template <int OUTMODE>
static __device__ __forceinline__ void gemm256_body(
    const bf16* __restrict__ A, const bf16* __restrict__ W,
    const float* __restrict__ bias, void* __restrict__ outp, int m0, int n0) {
  extern __shared__ __align__(16) bf16 dynls[];

  const int tid = threadIdx.x;
  const int lane = tid & 63, w = tid >> 6;
  const int wm = w >> 2, wn = w & 3;
  const int g = lane >> 4, r0 = lane & 15;

  f32x4 acc[4][4];
  const f32x4 vzero = {0.f, 0.f, 0.f, 0.f};
#pragma unroll
  for (int i = 0; i < 4; ++i)
#pragma unroll
    for (int j = 0; j < 4; ++j) acc[i][j] = vzero;

  const bf16* Abase = A + (size_t)m0 * DMODEL;
  const bf16* Wbase = W + (size_t)n0 * DMODEL;

  auto stage_a = [&](int kt, int buf) {
    const bf16* asrc = Abase + kt * 64;
    const bf16* bsrc = Wbase + kt * 64;
    bf16* sBuf = dynls + buf * BUFELEMS;
#pragma unroll
    for (int p = 0; p < 2; ++p) {
      int ch = tid + p * 512;
      int row = ch >> 3, c = (ch & 7) ^ (row & 7);
      async_ld16(asrc + (size_t)row * DMODEL + c * 8, sBuf + ch * 8);
    }
    {
      int ch = tid;
      int row = ch >> 3, c = (ch & 7) ^ (row & 7);
      async_ld16(bsrc + (size_t)row * DMODEL + c * 8, sBuf + 128 * 64 + ch * 8);
    }
  };
  auto stage_b = [&](int kt, int buf) {
    const bf16* bsrc = Wbase + kt * 64;
    bf16* sBuf = dynls + buf * BUFELEMS + 128 * 64;
#pragma unroll
    for (int p = 1; p < 4; ++p) {
      int ch = tid + p * 512;
      int row = ch >> 3, c = (ch & 7) ^ (row & 7);
      async_ld16(bsrc + (size_t)row * DMODEL + c * 8, sBuf + ch * 8);
    }
  };

  const int NT = DMODEL / 64;  // 32
  stage_a(0, 0); stage_b(0, 0);
  stage_a(1, 1); stage_b(1, 1);
  asm volatile("s_waitcnt vmcnt(6)" ::: "memory");
  __builtin_amdgcn_s_barrier();

  for (int kt = 0; kt < NT; ++kt) {
    const bf16* sA = dynls + (kt % 3) * BUFELEMS;
    const bf16* sB = sA + 128 * 64;
    const bool pf = (kt + 2) < NT;
    const int nb = (kt + 2) % 3;

#pragma unroll
    for (int ks = 0; ks < 2; ++ks) {
      bf16x8 af[4], bfr[4];
      const int cc = ks * 4 + g;
#pragma unroll
      for (int i = 0; i < 4; ++i) {
        int ra = wm * 64 + i * 16 + r0;
        af[i] = *(const bf16x8*)(sA + ra * 64 + ((cc ^ (ra & 7)) << 3));
        int rb = wn * 64 + i * 16 + r0;
        bfr[i] = *(const bf16x8*)(sB + rb * 64 + ((cc ^ (rb & 7)) << 3));
      }
      if (ks == 0) {
        if (pf) stage_a(kt + 2, nb);
      } else {
        if (pf) {
          stage_b(kt + 2, nb);
          asm volatile("s_waitcnt vmcnt(6)" ::: "memory");
        } else {
          asm volatile("s_waitcnt vmcnt(0)" ::: "memory");
        }
      }
      __builtin_amdgcn_sched_barrier(0);
      __builtin_amdgcn_s_barrier();
      __builtin_amdgcn_sched_barrier(0);
      __builtin_amdgcn_s_setprio(1);
#pragma unroll
      for (int i = 0; i < 4; ++i)
#pragma unroll
        for (int j = 0; j < 4; ++j)
          acc[i][j] = __builtin_amdgcn_mfma_f32_16x16x32_bf16(af[i], bfr[j],
                                                              acc[i][j], 0, 0, 0);
      __builtin_amdgcn_s_setprio(0);
    }
  }

#pragma unroll
  for (int i = 0; i < 4; ++i) {
#pragma unroll
    for (int j = 0; j < 4; ++j) {
      int mb = m0 + wm * 64 + i * 16 + g * 4;
      int n = n0 + wn * 64 + j * 16 + r0;
      float bn = bias[n];
      if (OUTMODE == 2) {
        float* o = (float*)outp;
#pragma unroll
        for (int r = 0; r < 4; ++r)
          o[(size_t)(mb + r) * DMODEL + n] = acc[i][j][r] + bn;
      } else {
        bf16* o = (bf16*)outp;
        int bb = mb >> 11, s = mb & (NSEQ - 1);
        bf16x4 pk;
#pragma unroll
        for (int r = 0; r < 4; ++r) pk[r] = (bf16)(acc[i][j][r] + bn);
        *(bf16x4*)(o + (size_t)(bb * DMODEL + n) * NSEQ + s) = pk;
      }
    }
  }
}

__global__ __launch_bounds__(512, 2) void k_gemm_v(
    const bf16* __restrict__ xb, const bf16* __restrict__ wv,
    const float* __restrict__ bv, bf16* __restrict__ vt) {
  gemm256_body<1>(xb, wv, bv, vt, blockIdx.y * 128, blockIdx.x * 256);
}

__global__ __launch_bounds__(512, 2) void k_gemm_out(
    const bf16* __restrict__ ab, const bf16* __restrict__ wo,
    const float* __restrict__ bo, float* __restrict__ out) {
  gemm256_body<2>(ab, wo, bo, out, blockIdx.y * 128, blockIdx.x * 256);
}

// ---------------------------------------------------------------------------
// Fused RMSNorm + RoPE.  Q pre-scaled by (1/sqrt(HD)) * log2(e) so attention
// softmax runs natively in the exp2 domain.
// ---------------------------------------------------------------------------
__global__ __launch_bounds__(256) void k_norm_rope(
    bf16* __restrict__ q, bf16* __restrict__ kk, const float* __restrict__ gq,
    const float* __restrict__ gk, const float* __restrict__ freqs) {
  int bidx = blockIdx.x;
  bf16* buf = (bidx < MTOT) ? q : kk;
  const float* gw = (bidx < MTOT) ? gq : gk;
  float qs = (bidx < MTOT) ? (0.08838834764831845f * 1.4426950408889634f)
                           : 1.0f;
  int row = bidx & (MTOT - 1);
  int s = row & (NSEQ - 1);
  int tid = threadIdx.x;
  int i0 = tid * 8;
  bf16* ptr = buf + (size_t)row * DMODEL + i0;
  bf16x8 v = *(const bf16x8*)ptr;
  float x[8];
  float ssq = 0.f;
#pragma unroll
  for (int j = 0; j < 8; ++j) {
    x[j] = (float)v[j];
    ssq += x[j] * x[j];
  }
#pragma unroll
  for (int off = 1; off < 64; off <<= 1) ssq += __shfl_xor(ssq, off);
  __shared__ float part[4];
  if ((tid & 63) == 0) part[tid >> 6] = ssq;
  __syncthreads();
  float tot = part[0] + part[1] + part[2] + part[3];
  float sc = rsqrtf(tot * (1.f / DMODEL) + 1e-6f) * qs;
  float4 g0 = *(const float4*)(gw + i0);
  float4 g1 = *(const float4*)(gw + i0 + 4);
  float y[8];
  y[0] = x[0] * sc * g0.x; y[1] = x[1] * sc * g0.y;
  y[2] = x[2] * sc * g0.z; y[3] = x[3] * sc * g0.w;
  y[4] = x[4] * sc * g1.x; y[5] = x[5] * sc * g1.y;
  y[6] = x[6] * sc * g1.z; y[7] = x[7] * sc * g1.w;
  int dl = i0 & (HDIM - 1);
  const float* fp = freqs + (size_t)s * HDIM + dl;
  float4 f0 = *(const float4*)fp;
  float4 f1 = *(const float4*)(fp + 4);
  bf16x8 out;
  out[0] = (bf16)(y[0] * f0.x - y[1] * f0.y);
  out[1] = (bf16)(y[0] * f0.y + y[1] * f0.x);
  out[2] = (bf16)(y[2] * f0.z - y[3] * f0.w);
  out[3] = (bf16)(y[2] * f0.w + y[3] * f0.z);
  out[4] = (bf16)(y[4] * f1.x - y[5] * f1.y);
  out[5] = (bf16)(y[4] * f1.y + y[5] * f1.x);
  out[6] = (bf16)(y[6] * f1.z - y[7] * f1.w);
  out[7] = (bf16)(y[6] * f1.w + y[7] * f1.z);
  *(bf16x8*)ptr = out;
}

// ---------------------------------------------------------------------------
// Flash attention v7b: KVB=32 (LDS 32KB -> 4+ blocks/CU) with the R12 spill
// bug fixed: __launch_bounds__(256, 2) lets the allocator keep ~100 VGPRs
// (R12's (256,4) cap forced scratch spills -- VGPR 64, +18MB writes).
// Algebra identical to R12 (correctness-verified).
// ---------------------------------------------------------------------------
#define LOG2E_THR 11.541560327111707f  // 8 * log2(e)
#define KVB 32

__global__ __launch_bounds__(256, 2) void k_attn(const bf16* __restrict__ q,
                                                 const bf16* __restrict__ k,
                                                 const bf16* __restrict__ vt,
                                                 bf16* __restrict__ o) {
  __shared__ __align__(16) bf16 sk[2][KVB * 128];   // 8KB per buf
  __shared__ __align__(16) bf16 sv[2][KVB * 128];   // 32 quad-rows x 256B
  const int bid = blockIdx.x;
  const int idx = bid >> 3;
  const int bh = (bid & 7) * 4 + (idx >> 4);  // 4 bh per XCD
  const int qt = idx & 15;
  const int bb = bh >> 4, h = bh & 15;
  const int tid = threadIdx.x;
  const int lane = tid & 63, w = tid >> 6;
  const int l31 = lane & 31, b5 = lane >> 5;

  // Q fragments (pre-scaled by log2e/sqrt(HD)): qf[kk] = Q[q0+l31][16kk+8b5+j]
  bf16x8 qf[8];
  {
    const bf16* qb =
        q + (size_t)(bb * NSEQ + qt * 128 + w * 32 + l31) * DMODEL + h * HDIM +
        b5 * 8;
#pragma unroll
    for (int kk = 0; kk < 8; ++kk) qf[kk] = *(const bf16x8*)(qb + kk * 16);
  }

  f32x16 oacc[4];
#pragma unroll
  for (int dt = 0; dt < 4; ++dt)
#pragma unroll
    for (int r = 0; r < 16; ++r) oacc[dt][r] = 0.f;
  f32x16 sum_acc;
#pragma unroll
  for (int r = 0; r < 16; ++r) sum_acc[r] = 0.f;
  float m = 0.f;  // log2 domain

  union { uint32_t u[4]; bf16x8 v; } ones;
  ones.u[0] = ones.u[1] = ones.u[2] = ones.u[3] = 0x3F803F80u;  // 1.0 bf16 x2

  const bf16* kbase = k + (size_t)(bb * NSEQ) * DMODEL + h * HDIM;
  const bf16* vbase = vt + (size_t)(bb * DMODEL + h * HDIM) * NSEQ;

  auto stage = [&](int t, int buf) {
    int k0 = t * KVB;
#pragma unroll
    for (int p = 0; p < 2; ++p) {  // K: 32 rows x 16 chunks, swizzle row&15
      int ch = tid + p * 256;
      int row = ch >> 4, cs = ch & 15;
      int c = cs ^ (row & 15);
      async_ld16(kbase + (size_t)(k0 + row) * DMODEL + c * 8, &sk[buf][ch * 8]);
    }
#pragma unroll
    for (int p = 0; p < 2; ++p) {  // V: 32 quad-rows x 16 chunk-positions
      int ch = tid + p * 256;
      int r2 = ch >> 4, pos = ch & 15;
      int idxv = pos ^ (r2 & 15);
      int d = ((idxv >> 2) << 5) | r2;  // d-row 0..127
      int creal = idxv & 3;             // 8-elem chunk within 32 keys
      async_ld16(vbase + (size_t)d * NSEQ + k0 + creal * 8, &sv[buf][ch * 8]);
    }
  };

  stage(0, 0);
  for (int t = 0; t < NSEQ / KVB; ++t) {
    const int cur = t & 1;
    asm volatile("s_waitcnt vmcnt(0)" ::: "memory");
    __syncthreads();
    if (t + 1 < NSEQ / KVB) stage(t + 1, cur ^ 1);  // overlaps compute

    // S - m = K Q^T with C initialized to -m (log2 domain)
    f32x16 sacc;
#pragma unroll
    for (int r = 0; r < 16; ++r) sacc[r] = -m;
    __builtin_amdgcn_s_setprio(1);
#pragma unroll
    for (int kk = 0; kk < 8; ++kk) {
      const int c = 2 * kk + b5;
      bf16x8 kf = *(const bf16x8*)(&sk[cur][l31 * 128 + ((c ^ (l31 & 15)) << 3)]);
      sacc = __builtin_amdgcn_mfma_f32_32x32x16_bf16(kf, qf[kk], sacc, 0, 0, 0);
    }
    __builtin_amdgcn_s_setprio(0);

    // lane-local max for q = l31 (values are S - m)
    float t1[8];
#pragma unroll
    for (int i = 0; i < 8; ++i) t1[i] = fmaxf(sacc[2 * i], sacc[2 * i + 1]);
    float pm = fmaxf(fmaxf(t1[0], t1[1]), t1[2]);
    pm = fmaxf(fmaxf(pm, t1[3]), t1[4]);
    pm = fmaxf(fmaxf(pm, t1[5]), t1[6]);
    pm = fmaxf(pm, t1[7]);
    {
      uint2v r2 = __builtin_amdgcn_permlane32_swap(__float_as_uint(pm),
                                                   __float_as_uint(pm), false,
                                                   false);
      pm = fmaxf(__uint_as_float(r2.x), __uint_as_float(r2.y));
    }
    if (__any(pm > LOG2E_THR)) {  // defer-max (T13)
      float d = fmaxf(pm, 0.f);
      m += d;
      float alpha = exp2_hw(-d);
#pragma unroll
      for (int r = 0; r < 16; ++r) sum_acc[r] *= alpha;
#pragma unroll
      for (int dt = 0; dt < 4; ++dt)
#pragma unroll
        for (int r = 0; r < 16; ++r) oacc[dt][r] *= alpha;
#pragma unroll
      for (int r = 0; r < 16; ++r) sacc[r] -= d;
    }

    // P = exp2(S - m); pack to bf16 pairs
#pragma unroll
    for (int r = 0; r < 16; ++r) sacc[r] = exp2_hw(sacc[r]);
    uint32_t P2[8];
#pragma unroll
    for (int i = 0; i < 8; ++i)
      asm("v_cvt_pk_bf16_f32 %0, %1, %2"
          : "=v"(P2[i])
          : "v"(sacc[2 * i]), "v"(sacc[2 * i + 1]));

    // O^T += V^T P^T ; sum_acc += ones * P^T
    __builtin_amdgcn_s_setprio(1);
#pragma unroll
    for (int u = 0; u < 2; ++u) {
      union { uint32_t uw[4]; bf16x8 v; } pb;
      uint2v ra = __builtin_amdgcn_permlane32_swap(P2[4 * u], P2[4 * u + 2],
                                                   false, false);
      uint2v rb = __builtin_amdgcn_permlane32_swap(P2[4 * u + 1],
                                                   P2[4 * u + 3], false, false);
      pb.uw[0] = ra.x;
      pb.uw[1] = rb.x;
      pb.uw[2] = ra.y;
      pb.uw[3] = rb.y;
      const int c = 2 * u + b5;  // 8-key slice index within 32 keys
      sum_acc = __builtin_amdgcn_mfma_f32_32x32x16_bf16(ones.v, pb.v, sum_acc,
                                                        0, 0, 0);
#pragma unroll
      for (int dt = 0; dt < 4; ++dt) {
        const int pos = ((dt << 2) | c) ^ (l31 & 15);
        bf16x8 vf = *(const bf16x8*)(&sv[cur][l31 * 128 + pos * 8]);
        oacc[dt] = __builtin_amdgcn_mfma_f32_32x32x16_bf16(vf, pb.v, oacc[dt],
                                                           0, 0, 0);
      }
    }
    __builtin_amdgcn_s_setprio(0);
  }

  // epilogue: O[q=l31][d = 32dt + 8rg + 4b5 + e]; l = sum_acc[0]
  const float rl = 1.f / sum_acc[0];
  bf16* ob = o + (size_t)(bb * NSEQ + qt * 128 + w * 32 + l31) * DMODEL +
             h * HDIM;
#pragma unroll
  for (int dt = 0; dt < 4; ++dt) {
#pragma unroll
    for (int rg = 0; rg < 4; ++rg) {
      bf16x4 pk4;
#pragma unroll
      for (int e = 0; e < 4; ++e) pk4[e] = (bf16)(oacc[dt][rg * 4 + e] * rl);
      *(bf16x4*)(ob + dt * 32 + rg * 8 + b5 * 4) = pk4;
    }
  }
}

// ---------------------------------------------------------------------------
extern "C" void kernel_launch(void* const* d_in, const int* in_sizes, int n_in,
                              void* d_out, int out_size, void* d_ws,
                              size_t ws_size, hipStream_t stream) {
  (void)in_sizes; (void)n_in; (void)out_size; (void)ws_size;
  const float* x = (const float*)d_in[0];
  const float* freqs = (const float*)d_in[1];
  const float* wq = (const float*)d_in[2];
  const float* bq = (const float*)d_in[3];
  const float* wk = (const float*)d_in[4];
  const float* bk = (const float*)d_in[5];
  const float* wv = (const float*)d_in[6];
  const float* bv = (const float*)d_in[7];
  const float* wo = (const float*)d_in[8];
  const float* bo = (const float*)d_in[9];
  const float* gq = (const float*)d_in[10];
  const float* gk = (const float*)d_in[11];

  char* ws = (char*)d_ws;
  const size_t SZ_TOK = (size_t)MTOT * DMODEL * sizeof(bf16);
  const size_t SZ_W = (size_t)DMODEL * DMODEL * sizeof(bf16);
  bf16* xb = (bf16*)ws;                 // attn-out after qkv
  bf16* qb = (bf16*)(ws + SZ_TOK);
  bf16* kb = (bf16*)(ws + 2 * SZ_TOK);
  bf16* vtb = (bf16*)(ws + 3 * SZ_TOK);
  bf16* wqb = (bf16*)(ws + 4 * SZ_TOK);  // wo-bf16 after qk
  bf16* wkb = (bf16*)(ws + 4 * SZ_TOK + SZ_W);
  bf16* wvb = (bf16*)(ws + 4 * SZ_TOK + 2 * SZ_W);

  const int LDSB = 3 * BUFELEMS * (int)sizeof(bf16);  // 147456
  const int LDSQK = 2 * 32768 * (int)sizeof(bf16);    // 131072
  hipFuncSetAttribute((const void*)k_gemm_qk,
                      hipFuncAttributeMaxDynamicSharedMemorySize, LDSQK);
  hipFuncSetAttribute((const void*)k_gemm_v,
                      hipFuncAttributeMaxDynamicSharedMemorySize, LDSB);
  hipFuncSetAttribute((const void*)k_gemm_out,
                      hipFuncAttributeMaxDynamicSharedMemorySize, LDSB);

  k_cvt4<<<2048, 256, 0, stream>>>(x, wq, wk, wv, xb, wqb, wkb, wvb);

  k_gemm_qk<<<256, 512, LDSQK, stream>>>(xb, wqb, wkb, bq, bk, qb, kb);
  k_gemm_v<<<dim3(8, 32), 512, LDSB, stream>>>(xb, wvb, bv, vtb);

  k_cvt<<<1024, 256, 0, stream>>>(wo, wqb, (DMODEL * DMODEL) / 8);

  k_norm_rope<<<2 * MTOT, 256, 0, stream>>>(qb, kb, gq, gk, freqs);

  k_attn<<<512, 256, 0, stream>>>(qb, kb, vtb, xb);

  k_gemm_out<<<dim3(8, 32), 512, LDSB, stream>>>(xb, wqb, bo, (float*)d_out);
}

// Round 14
// 256.098 us; speedup vs baseline: 1.4519x; 1.0404x over previous
//
#include <hip/hip_runtime.h>
#include <hip/hip_bf16.h>
#include <stdint.h>

// ---------------------------------------------------------------------------
// SelfAttention block: out = (attn(rope(rms(xWq)), rope(rms(xWk)), xWv)) Wo
// B=2, N=2048, D=2048, H=16, HD=128.  All GEMMs + attention in bf16 MFMA.
// ---------------------------------------------------------------------------

typedef __bf16 bf16;
typedef __bf16 bf16x8 __attribute__((ext_vector_type(8)));
typedef __bf16 bf16x4 __attribute__((ext_vector_type(4)));
typedef float  f32x4  __attribute__((ext_vector_type(4)));
typedef float  f32x16 __attribute__((ext_vector_type(16)));
typedef unsigned int uint2v __attribute__((ext_vector_type(2)));

#define MTOT   4096   // B*N token rows
#define DMODEL 2048
#define NSEQ   2048
#define NHEAD  16
#define HDIM   128

static __device__ __forceinline__ void async_ld16(const void* g, void* l) {
  void* gnc = const_cast<void*>(g);
  __builtin_amdgcn_global_load_lds((__attribute__((address_space(1))) void*)gnc,
                                   (__attribute__((address_space(3))) void*)l,
                                   16, 0, 0);
}

static __device__ __forceinline__ float exp2_hw(float x) {
  float r;
  asm("v_exp_f32 %0, %1" : "=v"(r) : "v"(x));
  return r;
}

// ---------------------------------------------------------------------------
// Fused f32 -> bf16 converts: x, wq, wk, wv in one launch.
// ---------------------------------------------------------------------------
#define XG (MTOT * DMODEL / 8)      // 1048576 groups of 8
#define WG (DMODEL * DMODEL / 8)    // 524288

__global__ __launch_bounds__(256) void k_cvt4(
    const float* __restrict__ x, const float* __restrict__ wq,
    const float* __restrict__ wk, const float* __restrict__ wv,
    bf16* __restrict__ xb, bf16* __restrict__ wqb, bf16* __restrict__ wkb,
    bf16* __restrict__ wvb) {
  int stride = gridDim.x * blockDim.x;
  for (int i = blockIdx.x * blockDim.x + threadIdx.x; i < XG + 3 * WG;
       i += stride) {
    const float* src;
    bf16* dst;
    int off;
    if (i < XG) { src = x; dst = xb; off = i; }
    else if (i < XG + WG) { src = wq; dst = wqb; off = i - XG; }
    else if (i < XG + 2 * WG) { src = wk; dst = wkb; off = i - XG - WG; }
    else { src = wv; dst = wvb; off = i - XG - 2 * WG; }
    const float4* p = (const float4*)(src) + 2 * (size_t)off;
    float4 a = p[0], b = p[1];
    bf16x8 o;
    o[0] = (bf16)a.x; o[1] = (bf16)a.y; o[2] = (bf16)a.z; o[3] = (bf16)a.w;
    o[4] = (bf16)b.x; o[5] = (bf16)b.y; o[6] = (bf16)b.z; o[7] = (bf16)b.w;
    *((bf16x8*)(dst) + off) = o;
  }
}

__global__ __launch_bounds__(256) void k_cvt(const float* __restrict__ in,
                                             bf16* __restrict__ out, int n8) {
  int stride = gridDim.x * blockDim.x;
  for (int i = blockIdx.x * blockDim.x + threadIdx.x; i < n8; i += stride) {
    const float4* p = (const float4*)(in) + 2 * (size_t)i;
    float4 a = p[0], b = p[1];
    bf16x8 o;
    o[0] = (bf16)a.x; o[1] = (bf16)a.y; o[2] = (bf16)a.z; o[3] = (bf16)a.w;
    o[4] = (bf16)b.x; o[5] = (bf16)b.y; o[6] = (bf16)b.z; o[7] = (bf16)b.w;
    *((bf16x8*)(out) + i) = o;
  }
}

// ---------------------------------------------------------------------------
// GEMM qk (R10): 256x256 tile, 8 waves, wave tile 128x64, dbuf LDS 128KB,
// counted vmcnt(8), raw s_barrier.  Grid 256 = 1 balanced round.
// ---------------------------------------------------------------------------
__global__ __launch_bounds__(512, 2) void k_gemm_qk(
    const bf16* __restrict__ xb, const bf16* __restrict__ wq,
    const bf16* __restrict__ wk, const float* __restrict__ bq,
    const float* __restrict__ bk, bf16* __restrict__ q, bf16* __restrict__ k) {
  extern __shared__ __align__(16) bf16 dyn[];  // [2][A 16384 + B 16384]

  const int swz = (blockIdx.x & 7) * 32 + (blockIdx.x >> 3);  // XCD-grouped
  const int mt = swz >> 4, nt = swz & 15;
  const int sec = nt >> 3;
  const int m0 = mt * 256, n0 = (nt & 7) * 256;
  const bf16* W = sec ? wk : wq;
  const float* bias = sec ? bk : bq;
  bf16* outp = sec ? k : q;

  const int tid = threadIdx.x;
  const int lane = tid & 63, w = tid >> 6;
  const int wm = w >> 2, wn = w & 3;
  const int g = lane >> 4, r0 = lane & 15;

  f32x4 acc[8][4];
  const f32x4 vzero = {0.f, 0.f, 0.f, 0.f};
#pragma unroll
  for (int i = 0; i < 8; ++i)
#pragma unroll
    for (int j = 0; j < 4; ++j) acc[i][j] = vzero;

  const bf16* Abase = xb + (size_t)m0 * DMODEL;
  const bf16* Wbase = W + (size_t)n0 * DMODEL;

  auto stage = [&](int kt, int buf) {
    const bf16* asrc = Abase + kt * 64;
    const bf16* bsrc = Wbase + kt * 64;
    bf16* sA = dyn + buf * 32768;
    bf16* sB = sA + 16384;
#pragma unroll
    for (int p = 0; p < 4; ++p) {
      int ch = tid + p * 512;
      int row = ch >> 3, c = (ch & 7) ^ (row & 7);
      async_ld16(asrc + (size_t)row * DMODEL + c * 8, sA + ch * 8);
    }
#pragma unroll
    for (int p = 0; p < 4; ++p) {
      int ch = tid + p * 512;
      int row = ch >> 3, c = (ch & 7) ^ (row & 7);
      async_ld16(bsrc + (size_t)row * DMODEL + c * 8, sB + ch * 8);
    }
  };

  const int NT = DMODEL / 64;  // 32
  stage(0, 0);
  for (int kt = 0; kt < NT; ++kt) {
    const int cur = kt & 1;
    if (kt > 0) __builtin_amdgcn_s_barrier();
    if (kt + 1 < NT) {
      stage(kt + 1, cur ^ 1);
      asm volatile("s_waitcnt vmcnt(8)" ::: "memory");
    } else {
      asm volatile("s_waitcnt vmcnt(0)" ::: "memory");
    }
    __builtin_amdgcn_s_barrier();
    const bf16* sA = dyn + cur * 32768;
    const bf16* sB = sA + 16384;

    bf16x8 a0[8], a1[8], b0[4], b1[4];
#pragma unroll
    for (int i = 0; i < 4; ++i) {
      int ra = wm * 128 + i * 16 + r0;
#pragma unroll
      for (int ks = 0; ks < 2; ++ks) {
        int cc = ks * 4 + g;
        a0[i * 2 + ks] = *(const bf16x8*)(sA + ra * 64 + ((cc ^ (ra & 7)) << 3));
      }
    }
#pragma unroll
    for (int j = 0; j < 2; ++j) {
      int rb = wn * 64 + j * 16 + r0;
#pragma unroll
      for (int ks = 0; ks < 2; ++ks) {
        int cc = ks * 4 + g;
        b0[j * 2 + ks] = *(const bf16x8*)(sB + rb * 64 + ((cc ^ (rb & 7)) << 3));
      }
    }
#pragma unroll
    for (int j = 0; j < 2; ++j) {
      int rb = wn * 64 + 32 + j * 16 + r0;
#pragma unroll
      for (int ks = 0; ks < 2; ++ks) {
        int cc = ks * 4 + g;
        b1[j * 2 + ks] = *(const bf16x8*)(sB + rb * 64 + ((cc ^ (rb & 7)) << 3));
      }
    }
    __builtin_amdgcn_s_setprio(1);
#pragma unroll
    for (int i = 0; i < 4; ++i)
#pragma unroll
      for (int j = 0; j < 2; ++j)
#pragma unroll
        for (int ks = 0; ks < 2; ++ks)
          acc[i][j] = __builtin_amdgcn_mfma_f32_16x16x32_bf16(
              a0[i * 2 + ks], b0[j * 2 + ks], acc[i][j], 0, 0, 0);
    __builtin_amdgcn_s_setprio(0);
#pragma unroll
    for (int i = 0; i < 4; ++i) {
      int ra = wm * 128 + 64 + i * 16 + r0;
#pragma unroll
      for (int ks = 0; ks < 2; ++ks) {
        int cc = ks * 4 + g;
        a1[i * 2 + ks] = *(const bf16x8*)(sA + ra * 64 + ((cc ^ (ra & 7)) << 3));
      }
    }
    __builtin_amdgcn_s_setprio(1);
#pragma unroll
    for (int i = 0; i < 4; ++i)
#pragma unroll
      for (int j = 0; j < 2; ++j)
#pragma unroll
        for (int ks = 0; ks < 2; ++ks)
          acc[i][2 + j] = __builtin_amdgcn_mfma_f32_16x16x32_bf16(
              a0[i * 2 + ks], b1[j * 2 + ks], acc[i][2 + j], 0, 0, 0);
    __builtin_amdgcn_s_setprio(0);
    __builtin_amdgcn_s_setprio(1);
#pragma unroll
    for (int i = 0; i < 4; ++i)
#pragma unroll
      for (int j = 0; j < 2; ++j)
#pragma unroll
        for (int ks = 0; ks < 2; ++ks)
          acc[4 + i][j] = __builtin_amdgcn_mfma_f32_16x16x32_bf16(
              a1[i * 2 + ks], b0[j * 2 + ks], acc[4 + i][j], 0, 0, 0);
    __builtin_amdgcn_s_setprio(0);
    __builtin_amdgcn_s_setprio(1);
#pragma unroll
    for (int i = 0; i < 4; ++i)
#pragma unroll
      for (int j = 0; j < 2; ++j)
#pragma unroll
        for (int ks = 0; ks < 2; ++ks)
          acc[4 + i][2 + j] = __builtin_amdgcn_mfma_f32_16x16x32_bf16(
              a1[i * 2 + ks], b1[j * 2 + ks], acc[4 + i][2 + j], 0, 0, 0);
    __builtin_amdgcn_s_setprio(0);
  }

#pragma unroll
  for (int i = 0; i < 8; ++i) {
#pragma unroll
    for (int j = 0; j < 4; ++j) {
      int mb = m0 + wm * 128 + (i >> 2) * 64 + (i & 3) * 16 + g * 4;
      int n = n0 + wn * 64 + (j >> 1) * 32 + (j & 1) * 16 + r0;
      float bn = bias[n];
#pragma unroll
      for (int r = 0; r < 4; ++r)
        outp[(size_t)(mb + r) * DMODEL + n] = (bf16)(acc[i][j][r] + bn);
    }
  }
}

// ---------------------------------------------------------------------------
// GEMM v3 (R4 structure): 128x256 tile, triple-buffered LDS, counted
// vmcnt(6), raw s_barrier.  For v-projection (transposed) and out-projection.
// ---------------------------------------------------------------------------
#define BUFELEMS (384 * 64)   // 48KB per buffer (A 128x64 + B 256x64)

template <int OUTMODE>
static __device__ __forceinline__ void gemm256_body(
    const bf16* __restrict__ A, const bf16* __restrict__ W,
    const float* __restrict__ bias, void* __restrict__ outp, int m0, int n0) {
  extern __shared__ __align__(16) bf16 dynls[];

  const int tid = threadIdx.x;
  const int lane = tid & 63, w = tid >> 6;
  const int wm = w >> 2, wn = w & 3;
  const int g = lane >> 4, r0 = lane & 15;

  f32x4 acc[4][4];
  const f32x4 vzero = {0.f, 0.f, 0.f, 0.f};
#pragma unroll
  for (int i = 0; i < 4; ++i)
#pragma unroll
    for (int j = 0; j < 4; ++j) acc[i][j] = vzero;

  const bf16* Abase = A + (size_t)m0 * DMODEL;
  const bf16* Wbase = W + (size_t)n0 * DMODEL;

  auto stage_a = [&](int kt, int buf) {
    const bf16* asrc = Abase + kt * 64;
    const bf16* bsrc = Wbase + kt * 64;
    bf16* sBuf = dynls + buf * BUFELEMS;
#pragma unroll
    for (int p = 0; p < 2; ++p) {
      int ch = tid + p * 512;
      int row = ch >> 3, c = (ch & 7) ^ (row & 7);
      async_ld16(asrc + (size_t)row * DMODEL + c * 8, sBuf + ch * 8);
    }
    {
      int ch = tid;
      int row = ch >> 3, c = (ch & 7) ^ (row & 7);
      async_ld16(bsrc + (size_t)row * DMODEL + c * 8, sBuf + 128 * 64 + ch * 8);
    }
  };
  auto stage_b = [&](int kt, int buf) {
    const bf16* bsrc = Wbase + kt * 64;
    bf16* sBuf = dynls + buf * BUFELEMS + 128 * 64;
#pragma unroll
    for (int p = 1; p < 4; ++p) {
      int ch = tid + p * 512;
      int row = ch >> 3, c = (ch & 7) ^ (row & 7);
      async_ld16(bsrc + (size_t)row * DMODEL + c * 8, sBuf + ch * 8);
    }
  };

  const int NT = DMODEL / 64;  // 32
  stage_a(0, 0); stage_b(0, 0);
  stage_a(1, 1); stage_b(1, 1);
  asm volatile("s_waitcnt vmcnt(6)" ::: "memory");
  __builtin_amdgcn_s_barrier();

  for (int kt = 0; kt < NT; ++kt) {
    const bf16* sA = dynls + (kt % 3) * BUFELEMS;
    const bf16* sB = sA + 128 * 64;
    const bool pf = (kt + 2) < NT;
    const int nb = (kt + 2) % 3;

#pragma unroll
    for (int ks = 0; ks < 2; ++ks) {
      bf16x8 af[4], bfr[4];
      const int cc = ks * 4 + g;
#pragma unroll
      for (int i = 0; i < 4; ++i) {
        int ra = wm * 64 + i * 16 + r0;
        af[i] = *(const bf16x8*)(sA + ra * 64 + ((cc ^ (ra & 7)) << 3));
        int rb = wn * 64 + i * 16 + r0;
        bfr[i] = *(const bf16x8*)(sB + rb * 64 + ((cc ^ (rb & 7)) << 3));
      }
      if (ks == 0) {
        if (pf) stage_a(kt + 2, nb);
      } else {
        if (pf) {
          stage_b(kt + 2, nb);
          asm volatile("s_waitcnt vmcnt(6)" ::: "memory");
        } else {
          asm volatile("s_waitcnt vmcnt(0)" ::: "memory");
        }
      }
      __builtin_amdgcn_sched_barrier(0);
      __builtin_amdgcn_s_barrier();
      __builtin_amdgcn_sched_barrier(0);
      __builtin_amdgcn_s_setprio(1);
#pragma unroll
      for (int i = 0; i < 4; ++i)
#pragma unroll
        for (int j = 0; j < 4; ++j)
          acc[i][j] = __builtin_amdgcn_mfma_f32_16x16x32_bf16(af[i], bfr[j],
                                                              acc[i][j], 0, 0, 0);
      __builtin_amdgcn_s_setprio(0);
    }
  }

#pragma unroll
  for (int i = 0; i < 4; ++i) {
#pragma unroll
    for (int j = 0; j < 4; ++j) {
      int mb = m0 + wm * 64 + i * 16 + g * 4;
      int n = n0 + wn * 64 + j * 16 + r0;
      float bn = bias[n];
      if (OUTMODE == 2) {
        float* o = (float*)outp;
#pragma unroll
        for (int r = 0; r < 4; ++r)
          o[(size_t)(mb + r) * DMODEL + n] = acc[i][j][r] + bn;
      } else {
        bf16* o = (bf16*)outp;
        int bb = mb >> 11, s = mb & (NSEQ - 1);
        bf16x4 pk;
#pragma unroll
        for (int r = 0; r < 4; ++r) pk[r] = (bf16)(acc[i][j][r] + bn);
        *(bf16x4*)(o + (size_t)(bb * DMODEL + n) * NSEQ + s) = pk;
      }
    }
  }
}

__global__ __launch_bounds__(512, 2) void k_gemm_v(
    const bf16* __restrict__ xb, const bf16* __restrict__ wv,
    const float* __restrict__ bv, bf16* __restrict__ vt) {
  gemm256_body<1>(xb, wv, bv, vt, blockIdx.y * 128, blockIdx.x * 256);
}

__global__ __launch_bounds__(512, 2) void k_gemm_out(
    const bf16* __restrict__ ab, const bf16* __restrict__ wo,
    const float* __restrict__ bo, float* __restrict__ out) {
  gemm256_body<2>(ab, wo, bo, out, blockIdx.y * 128, blockIdx.x * 256);
}

// ---------------------------------------------------------------------------
// Fused RMSNorm + RoPE, one row per WAVE (64 lanes x 32 elems): no LDS, no
// barriers, shfl-only reduce.  4 rows/block, grid 2048.  Q pre-scaled by
// (1/sqrt(HD)) * log2(e) for exp2-domain softmax.
// ---------------------------------------------------------------------------
__global__ __launch_bounds__(256) void k_norm_rope(
    bf16* __restrict__ q, bf16* __restrict__ kk, const float* __restrict__ gq,
    const float* __restrict__ gk, const float* __restrict__ freqs) {
  const int gr = blockIdx.x * 4 + (threadIdx.x >> 6);  // global row 0..8191
  bf16* buf = (gr < MTOT) ? q : kk;
  const float* gw = (gr < MTOT) ? gq : gk;
  const float qs = (gr < MTOT)
                       ? (0.08838834764831845f * 1.4426950408889634f)
                       : 1.0f;
  const int row = gr & (MTOT - 1);
  const int s = row & (NSEQ - 1);
  const int lane = threadIdx.x & 63;

  bf16* ptr = buf + (size_t)row * DMODEL + lane * 8;
  bf16x8 v[4];
  float x[4][8];
  float ssq = 0.f;
#pragma unroll
  for (int j = 0; j < 4; ++j) {
    v[j] = *(const bf16x8*)(ptr + j * 512);
#pragma unroll
    for (int e = 0; e < 8; ++e) {
      x[j][e] = (float)v[j][e];
      ssq += x[j][e] * x[j][e];
    }
  }
#pragma unroll
  for (int off = 1; off < 64; off <<= 1) ssq += __shfl_xor(ssq, off);
  const float sc = rsqrtf(ssq * (1.f / DMODEL) + 1e-6f) * qs;

  // freqs: dl = (lane*8 + j*512) & 127 = (lane&15)*8  (j-invariant)
  const float* fp = freqs + (size_t)s * HDIM + (lane & 15) * 8;
  const float4 f0 = *(const float4*)fp;
  const float4 f1 = *(const float4*)(fp + 4);

#pragma unroll
  for (int j = 0; j < 4; ++j) {
    const int i0 = lane * 8 + j * 512;
    float4 g0 = *(const float4*)(gw + i0);
    float4 g1 = *(const float4*)(gw + i0 + 4);
    float y[8];
    y[0] = x[j][0] * sc * g0.x; y[1] = x[j][1] * sc * g0.y;
    y[2] = x[j][2] * sc * g0.z; y[3] = x[j][3] * sc * g0.w;
    y[4] = x[j][4] * sc * g1.x; y[5] = x[j][5] * sc * g1.y;
    y[6] = x[j][6] * sc * g1.z; y[7] = x[j][7] * sc * g1.w;
    bf16x8 out;
    out[0] = (bf16)(y[0] * f0.x - y[1] * f0.y);
    out[1] = (bf16)(y[0] * f0.y + y[1] * f0.x);
    out[2] = (bf16)(y[2] * f0.z - y[3] * f0.w);
    out[3] = (bf16)(y[2] * f0.w + y[3] * f0.z);
    out[4] = (bf16)(y[4] * f1.x - y[5] * f1.y);
    out[5] = (bf16)(y[4] * f1.y + y[5] * f1.x);
    out[6] = (bf16)(y[6] * f1.z - y[7] * f1.w);
    out[7] = (bf16)(y[6] * f1.w + y[7] * f1.z);
    *(bf16x8*)(ptr + j * 512) = out;
  }
}

// ---------------------------------------------------------------------------
// Flash attention v6 (R10 exact, known-good 82us): KVB=64, conflict-free V
// row-pair layout, ones-MFMA row-sum, max3 tree, exp2-domain softmax.
// ---------------------------------------------------------------------------
#define LOG2E_THR 11.541560327111707f  // 8 * log2(e)

__global__ __launch_bounds__(256, 2) void k_attn(const bf16* __restrict__ q,
                                                 const bf16* __restrict__ k,
                                                 const bf16* __restrict__ vt,
                                                 bf16* __restrict__ o) {
  __shared__ __align__(16) bf16 sk[2][64 * 128];
  __shared__ __align__(16) bf16 sv[2][64 * 128];  // 64 row-pairs x 128 elems
  const int bid = blockIdx.x;
  const int idx = bid >> 3;
  const int bh = (bid & 7) * 4 + (idx >> 4);  // 4 bh per XCD
  const int qt = idx & 15;
  const int bb = bh >> 4, h = bh & 15;
  const int tid = threadIdx.x;
  const int lane = tid & 63, w = tid >> 6;
  const int l31 = lane & 31, b5 = lane >> 5;

  bf16x8 qf[8];
  {
    const bf16* qb =
        q + (size_t)(bb * NSEQ + qt * 128 + w * 32 + l31) * DMODEL + h * HDIM +
        b5 * 8;
#pragma unroll
    for (int kk = 0; kk < 8; ++kk) qf[kk] = *(const bf16x8*)(qb + kk * 16);
  }

  f32x16 oacc[4];
#pragma unroll
  for (int dt = 0; dt < 4; ++dt)
#pragma unroll
    for (int r = 0; r < 16; ++r) oacc[dt][r] = 0.f;
  f32x16 sum_acc;
#pragma unroll
  for (int r = 0; r < 16; ++r) sum_acc[r] = 0.f;
  float m = 0.f;  // log2 domain

  union { uint32_t u[4]; bf16x8 v; } ones;
  ones.u[0] = ones.u[1] = ones.u[2] = ones.u[3] = 0x3F803F80u;  // 1.0 bf16 x2

  const bf16* kbase = k + (size_t)(bb * NSEQ) * DMODEL + h * HDIM;
  const bf16* vbase = vt + (size_t)(bb * DMODEL + h * HDIM) * NSEQ;

  auto stage = [&](int t, int buf) {
    int k0 = t * 64;
#pragma unroll
    for (int p = 0; p < 4; ++p) {  // K: 64 rows x 16 chunks, swizzle row&15
      int ch = tid + p * 256;
      int row = ch >> 4, cs = ch & 15;
      int c = cs ^ (row & 15);
      async_ld16(kbase + (size_t)(k0 + row) * DMODEL + c * 8, &sk[buf][ch * 8]);
    }
#pragma unroll
    for (int p = 0; p < 4; ++p) {  // V: 64 row-pairs x 16 chunk-positions
      int ch = tid + p * 256;
      int r2 = ch >> 4, pos = ch & 15;
      int idxv = pos ^ (r2 & 15);
      int d = ((idxv >> 3) << 6) | r2;  // d-row 0..127
      int creal = idxv & 7;
      async_ld16(vbase + (size_t)d * NSEQ + k0 + creal * 8, &sv[buf][ch * 8]);
    }
  };

  stage(0, 0);
  for (int t = 0; t < NSEQ / 64; ++t) {
    const int cur = t & 1;
    asm volatile("s_waitcnt vmcnt(0)" ::: "memory");
    __syncthreads();
    if (t + 1 < NSEQ / 64) stage(t + 1, cur ^ 1);  // overlaps compute

    f32x16 sacc[2];
#pragma unroll
    for (int s = 0; s < 2; ++s)
#pragma unroll
      for (int r = 0; r < 16; ++r) sacc[s][r] = -m;
    __builtin_amdgcn_s_setprio(1);
#pragma unroll
    for (int s = 0; s < 2; ++s) {
      const int row = s * 32 + l31;
#pragma unroll
      for (int kk = 0; kk < 8; ++kk) {
        const int c = 2 * kk + b5;
        bf16x8 kf = *(const bf16x8*)(&sk[cur][row * 128 + ((c ^ (row & 15)) << 3)]);
        sacc[s] = __builtin_amdgcn_mfma_f32_32x32x16_bf16(kf, qf[kk], sacc[s],
                                                          0, 0, 0);
      }
    }
    __builtin_amdgcn_s_setprio(0);

    float t1[8];
#pragma unroll
    for (int i = 0; i < 8; ++i) {
      t1[i] = fmaxf(fmaxf(sacc[0][2 * i], sacc[0][2 * i + 1]),
                    sacc[1][2 * i]);
      t1[i] = fmaxf(t1[i], sacc[1][2 * i + 1]);
    }
    float pm = fmaxf(fmaxf(t1[0], t1[1]), t1[2]);
    pm = fmaxf(fmaxf(pm, t1[3]), t1[4]);
    pm = fmaxf(fmaxf(pm, t1[5]), t1[6]);
    pm = fmaxf(pm, t1[7]);
    {
      uint2v r2 = __builtin_amdgcn_permlane32_swap(__float_as_uint(pm),
                                                   __float_as_uint(pm), false,
                                                   false);
      pm = fmaxf(__uint_as_float(r2.x), __uint_as_float(r2.y));
    }
    if (__any(pm > LOG2E_THR)) {  // defer-max (T13)
      float d = fmaxf(pm, 0.f);
      m += d;
      float alpha = exp2_hw(-d);
#pragma unroll
      for (int r = 0; r < 16; ++r) sum_acc[r] *= alpha;
#pragma unroll
      for (int dt = 0; dt < 4; ++dt)
#pragma unroll
        for (int r = 0; r < 16; ++r) oacc[dt][r] *= alpha;
#pragma unroll
      for (int s = 0; s < 2; ++s)
#pragma unroll
        for (int r = 0; r < 16; ++r) sacc[s][r] -= d;
    }

#pragma unroll
    for (int s = 0; s < 2; ++s)
#pragma unroll
      for (int r = 0; r < 16; ++r) sacc[s][r] = exp2_hw(sacc[s][r]);

    uint32_t P2[16];
#pragma unroll
    for (int s = 0; s < 2; ++s)
#pragma unroll
      for (int i = 0; i < 8; ++i)
        asm("v_cvt_pk_bf16_f32 %0, %1, %2"
            : "=v"(P2[s * 8 + i])
            : "v"(sacc[s][2 * i]), "v"(sacc[s][2 * i + 1]));

    __builtin_amdgcn_s_setprio(1);
#pragma unroll
    for (int s = 0; s < 2; ++s) {
#pragma unroll
      for (int u = 0; u < 2; ++u) {
        union { uint32_t uw[4]; bf16x8 v; } pb;
        uint2v ra = __builtin_amdgcn_permlane32_swap(P2[s * 8 + 4 * u],
                                                     P2[s * 8 + 4 * u + 2],
                                                     false, false);
        uint2v rb = __builtin_amdgcn_permlane32_swap(P2[s * 8 + 4 * u + 1],
                                                     P2[s * 8 + 4 * u + 3],
                                                     false, false);
        pb.uw[0] = ra.x;
        pb.uw[1] = rb.x;
        pb.uw[2] = ra.y;
        pb.uw[3] = rb.y;
        const int c = 4 * s + 2 * u + b5;
        sum_acc = __builtin_amdgcn_mfma_f32_32x32x16_bf16(ones.v, pb.v,
                                                          sum_acc, 0, 0, 0);
#pragma unroll
        for (int dt = 0; dt < 4; ++dt) {
          const int rv = dt * 32 + l31;
          const int r2v = rv & 63;
          const int pos = (((rv >> 6) << 3) | c) ^ (r2v & 15);
          bf16x8 vf = *(const bf16x8*)(&sv[cur][r2v * 128 + pos * 8]);
          oacc[dt] = __builtin_amdgcn_mfma_f32_32x32x16_bf16(vf, pb.v, oacc[dt],
                                                             0, 0, 0);
        }
      }
    }
    __builtin_amdgcn_s_setprio(0);
  }

  const float rl = 1.f / sum_acc[0];
  bf16* ob = o + (size_t)(bb * NSEQ + qt * 128 + w * 32 + l31) * DMODEL +
             h * HDIM;
#pragma unroll
  for (int dt = 0; dt < 4; ++dt) {
#pragma unroll
    for (int rg = 0; rg < 4; ++rg) {
      bf16x4 pk4;
#pragma unroll
      for (int e = 0; e < 4; ++e) pk4[e] = (bf16)(oacc[dt][rg * 4 + e] * rl);
      *(bf16x4*)(ob + dt * 32 + rg * 8 + b5 * 4) = pk4;
    }
  }
}

// ---------------------------------------------------------------------------
extern "C" void kernel_launch(void* const* d_in, const int* in_sizes, int n_in,
                              void* d_out, int out_size, void* d_ws,
                              size_t ws_size, hipStream_t stream) {
  (void)in_sizes; (void)n_in; (void)out_size; (void)ws_size;
  const float* x = (const float*)d_in[0];
  const float* freqs = (const float*)d_in[1];
  const float* wq = (const float*)d_in[2];
  const float* bq = (const float*)d_in[3];
  const float* wk = (const float*)d_in[4];
  const float* bk = (const float*)d_in[5];
  const float* wv = (const float*)d_in[6];
  const float* bv = (const float*)d_in[7];
  const float* wo = (const float*)d_in[8];
  const float* bo = (const float*)d_in[9];
  const float* gq = (const float*)d_in[10];
  const float* gk = (const float*)d_in[11];

  char* ws = (char*)d_ws;
  const size_t SZ_TOK = (size_t)MTOT * DMODEL * sizeof(bf16);
  const size_t SZ_W = (size_t)DMODEL * DMODEL * sizeof(bf16);
  bf16* xb = (bf16*)ws;                 // attn-out after qkv
  bf16* qb = (bf16*)(ws + SZ_TOK);
  bf16* kb = (bf16*)(ws + 2 * SZ_TOK);
  bf16* vtb = (bf16*)(ws + 3 * SZ_TOK);
  bf16* wqb = (bf16*)(ws + 4 * SZ_TOK);  // wo-bf16 after qk
  bf16* wkb = (bf16*)(ws + 4 * SZ_TOK + SZ_W);
  bf16* wvb = (bf16*)(ws + 4 * SZ_TOK + 2 * SZ_W);

  const int LDSB = 3 * BUFELEMS * (int)sizeof(bf16);  // 147456
  const int LDSQK = 2 * 32768 * (int)sizeof(bf16);    // 131072
  hipFuncSetAttribute((const void*)k_gemm_qk,
                      hipFuncAttributeMaxDynamicSharedMemorySize, LDSQK);
  hipFuncSetAttribute((const void*)k_gemm_v,
                      hipFuncAttributeMaxDynamicSharedMemorySize, LDSB);
  hipFuncSetAttribute((const void*)k_gemm_out,
                      hipFuncAttributeMaxDynamicSharedMemorySize, LDSB);

  k_cvt4<<<2048, 256, 0, stream>>>(x, wq, wk, wv, xb, wqb, wkb, wvb);

  k_gemm_qk<<<256, 512, LDSQK, stream>>>(xb, wqb, wkb, bq, bk, qb, kb);
  k_gemm_v<<<dim3(8, 32), 512, LDSB, stream>>>(xb, wvb, bv, vtb);

  k_cvt<<<1024, 256, 0, stream>>>(wo, wqb, (DMODEL * DMODEL) / 8);

  k_norm_rope<<<2048, 256, 0, stream>>>(qb, kb, gq, gk, freqs);

  k_attn<<<512, 256, 0, stream>>>(qb, kb, vtb, xb);

  k_gemm_out<<<dim3(8, 32), 512, LDSB, stream>>>(xb, wqb, bo, (float*)d_out);
}

// Round 15
// 253.352 us; speedup vs baseline: 1.4677x; 1.0108x over previous
//
#include <hip/hip_runtime.h>
#include <hip/hip_bf16.h>
#include <stdint.h>

// ---------------------------------------------------------------------------
// SelfAttention block: out = (attn(rope(rms(xWq)), rope(rms(xWk)), xWv)) Wo
// B=2, N=2048, D=2048, H=16, HD=128.  All GEMMs + attention in bf16 MFMA.
// ---------------------------------------------------------------------------

typedef __bf16 bf16;
typedef __bf16 bf16x8 __attribute__((ext_vector_type(8)));
typedef __bf16 bf16x4 __attribute__((ext_vector_type(4)));
typedef float  f32x4  __attribute__((ext_vector_type(4)));
typedef float  f32x16 __attribute__((ext_vector_type(16)));
typedef unsigned int uint2v __attribute__((ext_vector_type(2)));

#define MTOT   4096   // B*N token rows
#define DMODEL 2048
#define NSEQ   2048
#define NHEAD  16
#define HDIM   128

static __device__ __forceinline__ void async_ld16(const void* g, void* l) {
  void* gnc = const_cast<void*>(g);
  __builtin_amdgcn_global_load_lds((__attribute__((address_space(1))) void*)gnc,
                                   (__attribute__((address_space(3))) void*)l,
                                   16, 0, 0);
}

static __device__ __forceinline__ float exp2_hw(float x) {
  float r;
  asm("v_exp_f32 %0, %1" : "=v"(r) : "v"(x));
  return r;
}

// ---------------------------------------------------------------------------
// Fused f32 -> bf16 converts: x, wq, wk, wv, wo in ONE launch (5-way).
// ---------------------------------------------------------------------------
#define XG (MTOT * DMODEL / 8)      // 1048576 groups of 8
#define WG (DMODEL * DMODEL / 8)    // 524288

__global__ __launch_bounds__(256) void k_cvt5(
    const float* __restrict__ x, const float* __restrict__ wq,
    const float* __restrict__ wk, const float* __restrict__ wv,
    const float* __restrict__ wo, bf16* __restrict__ xb,
    bf16* __restrict__ wqb, bf16* __restrict__ wkb, bf16* __restrict__ wvb,
    bf16* __restrict__ wob) {
  int stride = gridDim.x * blockDim.x;
  for (int i = blockIdx.x * blockDim.x + threadIdx.x; i < XG + 4 * WG;
       i += stride) {
    const float* src;
    bf16* dst;
    int off;
    if (i < XG) { src = x; dst = xb; off = i; }
    else if (i < XG + WG) { src = wq; dst = wqb; off = i - XG; }
    else if (i < XG + 2 * WG) { src = wk; dst = wkb; off = i - XG - WG; }
    else if (i < XG + 3 * WG) { src = wv; dst = wvb; off = i - XG - 2 * WG; }
    else { src = wo; dst = wob; off = i - XG - 3 * WG; }
    const float4* p = (const float4*)(src) + 2 * (size_t)off;
    float4 a = p[0], b = p[1];
    bf16x8 o;
    o[0] = (bf16)a.x; o[1] = (bf16)a.y; o[2] = (bf16)a.z; o[3] = (bf16)a.w;
    o[4] = (bf16)b.x; o[5] = (bf16)b.y; o[6] = (bf16)b.z; o[7] = (bf16)b.w;
    *((bf16x8*)(dst) + off) = o;
  }
}

// ---------------------------------------------------------------------------
// GEMM qk (R10): 256x256 tile, 8 waves, wave tile 128x64, dbuf LDS 128KB,
// counted vmcnt(8), raw s_barrier.  Grid 256 = 1 balanced round.
// ---------------------------------------------------------------------------
__global__ __launch_bounds__(512, 2) void k_gemm_qk(
    const bf16* __restrict__ xb, const bf16* __restrict__ wq,
    const bf16* __restrict__ wk, const float* __restrict__ bq,
    const float* __restrict__ bk, bf16* __restrict__ q, bf16* __restrict__ k) {
  extern __shared__ __align__(16) bf16 dyn[];  // [2][A 16384 + B 16384]

  const int swz = (blockIdx.x & 7) * 32 + (blockIdx.x >> 3);  // XCD-grouped
  const int mt = swz >> 4, nt = swz & 15;
  const int sec = nt >> 3;
  const int m0 = mt * 256, n0 = (nt & 7) * 256;
  const bf16* W = sec ? wk : wq;
  const float* bias = sec ? bk : bq;
  bf16* outp = sec ? k : q;

  const int tid = threadIdx.x;
  const int lane = tid & 63, w = tid >> 6;
  const int wm = w >> 2, wn = w & 3;
  const int g = lane >> 4, r0 = lane & 15;

  f32x4 acc[8][4];
  const f32x4 vzero = {0.f, 0.f, 0.f, 0.f};
#pragma unroll
  for (int i = 0; i < 8; ++i)
#pragma unroll
    for (int j = 0; j < 4; ++j) acc[i][j] = vzero;

  const bf16* Abase = xb + (size_t)m0 * DMODEL;
  const bf16* Wbase = W + (size_t)n0 * DMODEL;

  auto stage = [&](int kt, int buf) {
    const bf16* asrc = Abase + kt * 64;
    const bf16* bsrc = Wbase + kt * 64;
    bf16* sA = dyn + buf * 32768;
    bf16* sB = sA + 16384;
#pragma unroll
    for (int p = 0; p < 4; ++p) {
      int ch = tid + p * 512;
      int row = ch >> 3, c = (ch & 7) ^ (row & 7);
      async_ld16(asrc + (size_t)row * DMODEL + c * 8, sA + ch * 8);
    }
#pragma unroll
    for (int p = 0; p < 4; ++p) {
      int ch = tid + p * 512;
      int row = ch >> 3, c = (ch & 7) ^ (row & 7);
      async_ld16(bsrc + (size_t)row * DMODEL + c * 8, sB + ch * 8);
    }
  };

  const int NT = DMODEL / 64;  // 32
  stage(0, 0);
  for (int kt = 0; kt < NT; ++kt) {
    const int cur = kt & 1;
    if (kt > 0) __builtin_amdgcn_s_barrier();
    if (kt + 1 < NT) {
      stage(kt + 1, cur ^ 1);
      asm volatile("s_waitcnt vmcnt(8)" ::: "memory");
    } else {
      asm volatile("s_waitcnt vmcnt(0)" ::: "memory");
    }
    __builtin_amdgcn_s_barrier();
    const bf16* sA = dyn + cur * 32768;
    const bf16* sB = sA + 16384;

    bf16x8 a0[8], a1[8], b0[4], b1[4];
#pragma unroll
    for (int i = 0; i < 4; ++i) {
      int ra = wm * 128 + i * 16 + r0;
#pragma unroll
      for (int ks = 0; ks < 2; ++ks) {
        int cc = ks * 4 + g;
        a0[i * 2 + ks] = *(const bf16x8*)(sA + ra * 64 + ((cc ^ (ra & 7)) << 3));
      }
    }
#pragma unroll
    for (int j = 0; j < 2; ++j) {
      int rb = wn * 64 + j * 16 + r0;
#pragma unroll
      for (int ks = 0; ks < 2; ++ks) {
        int cc = ks * 4 + g;
        b0[j * 2 + ks] = *(const bf16x8*)(sB + rb * 64 + ((cc ^ (rb & 7)) << 3));
      }
    }
#pragma unroll
    for (int j = 0; j < 2; ++j) {
      int rb = wn * 64 + 32 + j * 16 + r0;
#pragma unroll
      for (int ks = 0; ks < 2; ++ks) {
        int cc = ks * 4 + g;
        b1[j * 2 + ks] = *(const bf16x8*)(sB + rb * 64 + ((cc ^ (rb & 7)) << 3));
      }
    }
    __builtin_amdgcn_s_setprio(1);
#pragma unroll
    for (int i = 0; i < 4; ++i)
#pragma unroll
      for (int j = 0; j < 2; ++j)
#pragma unroll
        for (int ks = 0; ks < 2; ++ks)
          acc[i][j] = __builtin_amdgcn_mfma_f32_16x16x32_bf16(
              a0[i * 2 + ks], b0[j * 2 + ks], acc[i][j], 0, 0, 0);
    __builtin_amdgcn_s_setprio(0);
#pragma unroll
    for (int i = 0; i < 4; ++i) {
      int ra = wm * 128 + 64 + i * 16 + r0;
#pragma unroll
      for (int ks = 0; ks < 2; ++ks) {
        int cc = ks * 4 + g;
        a1[i * 2 + ks] = *(const bf16x8*)(sA + ra * 64 + ((cc ^ (ra & 7)) << 3));
      }
    }
    __builtin_amdgcn_s_setprio(1);
#pragma unroll
    for (int i = 0; i < 4; ++i)
#pragma unroll
      for (int j = 0; j < 2; ++j)
#pragma unroll
        for (int ks = 0; ks < 2; ++ks)
          acc[i][2 + j] = __builtin_amdgcn_mfma_f32_16x16x32_bf16(
              a0[i * 2 + ks], b1[j * 2 + ks], acc[i][2 + j], 0, 0, 0);
    __builtin_amdgcn_s_setprio(0);
    __builtin_amdgcn_s_setprio(1);
#pragma unroll
    for (int i = 0; i < 4; ++i)
#pragma unroll
      for (int j = 0; j < 2; ++j)
#pragma unroll
        for (int ks = 0; ks < 2; ++ks)
          acc[4 + i][j] = __builtin_amdgcn_mfma_f32_16x16x32_bf16(
              a1[i * 2 + ks], b0[j * 2 + ks], acc[4 + i][j], 0, 0, 0);
    __builtin_amdgcn_s_setprio(0);
    __builtin_amdgcn_s_setprio(1);
#pragma unroll
    for (int i = 0; i < 4; ++i)
#pragma unroll
      for (int j = 0; j < 2; ++j)
#pragma unroll
        for (int ks = 0; ks < 2; ++ks)
          acc[4 + i][2 + j] = __builtin_amdgcn_mfma_f32_16x16x32_bf16(
              a1[i * 2 + ks], b1[j * 2 + ks], acc[4 + i][2 + j], 0, 0, 0);
    __builtin_amdgcn_s_setprio(0);
  }

#pragma unroll
  for (int i = 0; i < 8; ++i) {
#pragma unroll
    for (int j = 0; j < 4; ++j) {
      int mb = m0 + wm * 128 + (i >> 2) * 64 + (i & 3) * 16 + g * 4;
      int n = n0 + wn * 64 + (j >> 1) * 32 + (j & 1) * 16 + r0;
      float bn = bias[n];
#pragma unroll
      for (int r = 0; r < 4; ++r)
        outp[(size_t)(mb + r) * DMODEL + n] = (bf16)(acc[i][j][r] + bn);
    }
  }
}

// ---------------------------------------------------------------------------
// GEMM v3 (R4 structure): 128x256 tile, triple-buffered LDS, counted
// vmcnt(6), raw s_barrier.  For v-projection (transposed) and out-projection.
// ---------------------------------------------------------------------------
#define BUFELEMS (384 * 64)   // 48KB per buffer (A 128x64 + B 256x64)

template <int OUTMODE>
static __device__ __forceinline__ void gemm256_body(
    const bf16* __restrict__ A, const bf16* __restrict__ W,
    const float* __restrict__ bias, void* __restrict__ outp, int m0, int n0) {
  extern __shared__ __align__(16) bf16 dynls[];

  const int tid = threadIdx.x;
  const int lane = tid & 63, w = tid >> 6;
  const int wm = w >> 2, wn = w & 3;
  const int g = lane >> 4, r0 = lane & 15;

  f32x4 acc[4][4];
  const f32x4 vzero = {0.f, 0.f, 0.f, 0.f};
#pragma unroll
  for (int i = 0; i < 4; ++i)
#pragma unroll
    for (int j = 0; j < 4; ++j) acc[i][j] = vzero;

  const bf16* Abase = A + (size_t)m0 * DMODEL;
  const bf16* Wbase = W + (size_t)n0 * DMODEL;

  auto stage_a = [&](int kt, int buf) {
    const bf16* asrc = Abase + kt * 64;
    const bf16* bsrc = Wbase + kt * 64;
    bf16* sBuf = dynls + buf * BUFELEMS;
#pragma unroll
    for (int p = 0; p < 2; ++p) {
      int ch = tid + p * 512;
      int row = ch >> 3, c = (ch & 7) ^ (row & 7);
      async_ld16(asrc + (size_t)row * DMODEL + c * 8, sBuf + ch * 8);
    }
    {
      int ch = tid;
      int row = ch >> 3, c = (ch & 7) ^ (row & 7);
      async_ld16(bsrc + (size_t)row * DMODEL + c * 8, sBuf + 128 * 64 + ch * 8);
    }
  };
  auto stage_b = [&](int kt, int buf) {
    const bf16* bsrc = Wbase + kt * 64;
    bf16* sBuf = dynls + buf * BUFELEMS + 128 * 64;
#pragma unroll
    for (int p = 1; p < 4; ++p) {
      int ch = tid + p * 512;
      int row = ch >> 3, c = (ch & 7) ^ (row & 7);
      async_ld16(bsrc + (size_t)row * DMODEL + c * 8, sBuf + ch * 8);
    }
  };

  const int NT = DMODEL / 64;  // 32
  stage_a(0, 0); stage_b(0, 0);
  stage_a(1, 1); stage_b(1, 1);
  asm volatile("s_waitcnt vmcnt(6)" ::: "memory");
  __builtin_amdgcn_s_barrier();

  for (int kt = 0; kt < NT; ++kt) {
    const bf16* sA = dynls + (kt % 3) * BUFELEMS;
    const bf16* sB = sA + 128 * 64;
    const bool pf = (kt + 2) < NT;
    const int nb = (kt + 2) % 3;

#pragma unroll
    for (int ks = 0; ks < 2; ++ks) {
      bf16x8 af[4], bfr[4];
      const int cc = ks * 4 + g;
#pragma unroll
      for (int i = 0; i < 4; ++i) {
        int ra = wm * 64 + i * 16 + r0;
        af[i] = *(const bf16x8*)(sA + ra * 64 + ((cc ^ (ra & 7)) << 3));
        int rb = wn * 64 + i * 16 + r0;
        bfr[i] = *(const bf16x8*)(sB + rb * 64 + ((cc ^ (rb & 7)) << 3));
      }
      if (ks == 0) {
        if (pf) stage_a(kt + 2, nb);
      } else {
        if (pf) {
          stage_b(kt + 2, nb);
          asm volatile("s_waitcnt vmcnt(6)" ::: "memory");
        } else {
          asm volatile("s_waitcnt vmcnt(0)" ::: "memory");
        }
      }
      __builtin_amdgcn_sched_barrier(0);
      __builtin_amdgcn_s_barrier();
      __builtin_amdgcn_sched_barrier(0);
      __builtin_amdgcn_s_setprio(1);
#pragma unroll
      for (int i = 0; i < 4; ++i)
#pragma unroll
        for (int j = 0; j < 4; ++j)
          acc[i][j] = __builtin_amdgcn_mfma_f32_16x16x32_bf16(af[i], bfr[j],
                                                              acc[i][j], 0, 0, 0);
      __builtin_amdgcn_s_setprio(0);
    }
  }

#pragma unroll
  for (int i = 0; i < 4; ++i) {
#pragma unroll
    for (int j = 0; j < 4; ++j) {
      int mb = m0 + wm * 64 + i * 16 + g * 4;
      int n = n0 + wn * 64 + j * 16 + r0;
      float bn = bias[n];
      if (OUTMODE == 2) {
        float* o = (float*)outp;
#pragma unroll
        for (int r = 0; r < 4; ++r)
          o[(size_t)(mb + r) * DMODEL + n] = acc[i][j][r] + bn;
      } else {
        bf16* o = (bf16*)outp;
        int bb = mb >> 11, s = mb & (NSEQ - 1);
        bf16x4 pk;
#pragma unroll
        for (int r = 0; r < 4; ++r) pk[r] = (bf16)(acc[i][j][r] + bn);
        *(bf16x4*)(o + (size_t)(bb * DMODEL + n) * NSEQ + s) = pk;
      }
    }
  }
}

__global__ __launch_bounds__(512, 2) void k_gemm_v(
    const bf16* __restrict__ xb, const bf16* __restrict__ wv,
    const float* __restrict__ bv, bf16* __restrict__ vt) {
  gemm256_body<1>(xb, wv, bv, vt, blockIdx.y * 128, blockIdx.x * 256);
}

__global__ __launch_bounds__(512, 2) void k_gemm_out(
    const bf16* __restrict__ ab, const bf16* __restrict__ wo,
    const float* __restrict__ bo, float* __restrict__ out) {
  gemm256_body<2>(ab, wo, bo, out, blockIdx.y * 128, blockIdx.x * 256);
}

// ---------------------------------------------------------------------------
// Fused RMSNorm + RoPE, one row per WAVE (64 lanes x 32 elems): no LDS, no
// barriers, shfl-only reduce.  4 rows/block, grid 2048.  Q pre-scaled by
// (1/sqrt(HD)) * log2(e) for exp2-domain softmax.
// ---------------------------------------------------------------------------
__global__ __launch_bounds__(256) void k_norm_rope(
    bf16* __restrict__ q, bf16* __restrict__ kk, const float* __restrict__ gq,
    const float* __restrict__ gk, const float* __restrict__ freqs) {
  const int gr = blockIdx.x * 4 + (threadIdx.x >> 6);  // global row 0..8191
  bf16* buf = (gr < MTOT) ? q : kk;
  const float* gw = (gr < MTOT) ? gq : gk;
  const float qs = (gr < MTOT)
                       ? (0.08838834764831845f * 1.4426950408889634f)
                       : 1.0f;
  const int row = gr & (MTOT - 1);
  const int s = row & (NSEQ - 1);
  const int lane = threadIdx.x & 63;

  bf16* ptr = buf + (size_t)row * DMODEL + lane * 8;
  bf16x8 v[4];
  float x[4][8];
  float ssq = 0.f;
#pragma unroll
  for (int j = 0; j < 4; ++j) {
    v[j] = *(const bf16x8*)(ptr + j * 512);
#pragma unroll
    for (int e = 0; e < 8; ++e) {
      x[j][e] = (float)v[j][e];
      ssq += x[j][e] * x[j][e];
    }
  }
#pragma unroll
  for (int off = 1; off < 64; off <<= 1) ssq += __shfl_xor(ssq, off);
  const float sc = rsqrtf(ssq * (1.f / DMODEL) + 1e-6f) * qs;

  const float* fp = freqs + (size_t)s * HDIM + (lane & 15) * 8;
  const float4 f0 = *(const float4*)fp;
  const float4 f1 = *(const float4*)(fp + 4);

#pragma unroll
  for (int j = 0; j < 4; ++j) {
    const int i0 = lane * 8 + j * 512;
    float4 g0 = *(const float4*)(gw + i0);
    float4 g1 = *(const float4*)(gw + i0 + 4);
    float y[8];
    y[0] = x[j][0] * sc * g0.x; y[1] = x[j][1] * sc * g0.y;
    y[2] = x[j][2] * sc * g0.z; y[3] = x[j][3] * sc * g0.w;
    y[4] = x[j][4] * sc * g1.x; y[5] = x[j][5] * sc * g1.y;
    y[6] = x[j][6] * sc * g1.z; y[7] = x[j][7] * sc * g1.w;
    bf16x8 out;
    out[0] = (bf16)(y[0] * f0.x - y[1] * f0.y);
    out[1] = (bf16)(y[0] * f0.y + y[1] * f0.x);
    out[2] = (bf16)(y[2] * f0.z - y[3] * f0.w);
    out[3] = (bf16)(y[2] * f0.w + y[3] * f0.z);
    out[4] = (bf16)(y[4] * f1.x - y[5] * f1.y);
    out[5] = (bf16)(y[4] * f1.y + y[5] * f1.x);
    out[6] = (bf16)(y[6] * f1.z - y[7] * f1.w);
    out[7] = (bf16)(y[6] * f1.w + y[7] * f1.z);
    *(bf16x8*)(ptr + j * 512) = out;
  }
}

// ---------------------------------------------------------------------------
// Flash attention v6 (R10/R14 exact, known-good 82us): KVB=64, conflict-free
// V row-pair layout, ones-MFMA row-sum, max3 tree, exp2-domain softmax.
// ---------------------------------------------------------------------------
#define LOG2E_THR 11.541560327111707f  // 8 * log2(e)

__global__ __launch_bounds__(256, 2) void k_attn(const bf16* __restrict__ q,
                                                 const bf16* __restrict__ k,
                                                 const bf16* __restrict__ vt,
                                                 bf16* __restrict__ o) {
  __shared__ __align__(16) bf16 sk[2][64 * 128];
  __shared__ __align__(16) bf16 sv[2][64 * 128];  // 64 row-pairs x 128 elems
  const int bid = blockIdx.x;
  const int idx = bid >> 3;
  const int bh = (bid & 7) * 4 + (idx >> 4);  // 4 bh per XCD
  const int qt = idx & 15;
  const int bb = bh >> 4, h = bh & 15;
  const int tid = threadIdx.x;
  const int lane = tid & 63, w = tid >> 6;
  const int l31 = lane & 31, b5 = lane >> 5;

  bf16x8 qf[8];
  {
    const bf16* qb =
        q + (size_t)(bb * NSEQ + qt * 128 + w * 32 + l31) * DMODEL + h * HDIM +
        b5 * 8;
#pragma unroll
    for (int kk = 0; kk < 8; ++kk) qf[kk] = *(const bf16x8*)(qb + kk * 16);
  }

  f32x16 oacc[4];
#pragma unroll
  for (int dt = 0; dt < 4; ++dt)
#pragma unroll
    for (int r = 0; r < 16; ++r) oacc[dt][r] = 0.f;
  f32x16 sum_acc;
#pragma unroll
  for (int r = 0; r < 16; ++r) sum_acc[r] = 0.f;
  float m = 0.f;  // log2 domain

  union { uint32_t u[4]; bf16x8 v; } ones;
  ones.u[0] = ones.u[1] = ones.u[2] = ones.u[3] = 0x3F803F80u;  // 1.0 bf16 x2

  const bf16* kbase = k + (size_t)(bb * NSEQ) * DMODEL + h * HDIM;
  const bf16* vbase = vt + (size_t)(bb * DMODEL + h * HDIM) * NSEQ;

  auto stage = [&](int t, int buf) {
    int k0 = t * 64;
#pragma unroll
    for (int p = 0; p < 4; ++p) {  // K: 64 rows x 16 chunks, swizzle row&15
      int ch = tid + p * 256;
      int row = ch >> 4, cs = ch & 15;
      int c = cs ^ (row & 15);
      async_ld16(kbase + (size_t)(k0 + row) * DMODEL + c * 8, &sk[buf][ch * 8]);
    }
#pragma unroll
    for (int p = 0; p < 4; ++p) {  // V: 64 row-pairs x 16 chunk-positions
      int ch = tid + p * 256;
      int r2 = ch >> 4, pos = ch & 15;
      int idxv = pos ^ (r2 & 15);
      int d = ((idxv >> 3) << 6) | r2;  // d-row 0..127
      int creal = idxv & 7;
      async_ld16(vbase + (size_t)d * NSEQ + k0 + creal * 8, &sv[buf][ch * 8]);
    }
  };

  stage(0, 0);
  for (int t = 0; t < NSEQ / 64; ++t) {
    const int cur = t & 1;
    asm volatile("s_waitcnt vmcnt(0)" ::: "memory");
    __syncthreads();
    if (t + 1 < NSEQ / 64) stage(t + 1, cur ^ 1);  // overlaps compute

    f32x16 sacc[2];
#pragma unroll
    for (int s = 0; s < 2; ++s)
#pragma unroll
      for (int r = 0; r < 16; ++r) sacc[s][r] = -m;
    __builtin_amdgcn_s_setprio(1);
#pragma unroll
    for (int s = 0; s < 2; ++s) {
      const int row = s * 32 + l31;
#pragma unroll
      for (int kk = 0; kk < 8; ++kk) {
        const int c = 2 * kk + b5;
        bf16x8 kf = *(const bf16x8*)(&sk[cur][row * 128 + ((c ^ (row & 15)) << 3)]);
        sacc[s] = __builtin_amdgcn_mfma_f32_32x32x16_bf16(kf, qf[kk], sacc[s],
                                                          0, 0, 0);
      }
    }
    __builtin_amdgcn_s_setprio(0);

    float t1[8];
#pragma unroll
    for (int i = 0; i < 8; ++i) {
      t1[i] = fmaxf(fmaxf(sacc[0][2 * i], sacc[0][2 * i + 1]),
                    sacc[1][2 * i]);
      t1[i] = fmaxf(t1[i], sacc[1][2 * i + 1]);
    }
    float pm = fmaxf(fmaxf(t1[0], t1[1]), t1[2]);
    pm = fmaxf(fmaxf(pm, t1[3]), t1[4]);
    pm = fmaxf(fmaxf(pm, t1[5]), t1[6]);
    pm = fmaxf(pm, t1[7]);
    {
      uint2v r2 = __builtin_amdgcn_permlane32_swap(__float_as_uint(pm),
                                                   __float_as_uint(pm), false,
                                                   false);
      pm = fmaxf(__uint_as_float(r2.x), __uint_as_float(r2.y));
    }
    if (__any(pm > LOG2E_THR)) {  // defer-max (T13)
      float d = fmaxf(pm, 0.f);
      m += d;
      float alpha = exp2_hw(-d);
#pragma unroll
      for (int r = 0; r < 16; ++r) sum_acc[r] *= alpha;
#pragma unroll
      for (int dt = 0; dt < 4; ++dt)
#pragma unroll
        for (int r = 0; r < 16; ++r) oacc[dt][r] *= alpha;
#pragma unroll
      for (int s = 0; s < 2; ++s)
#pragma unroll
        for (int r = 0; r < 16; ++r) sacc[s][r] -= d;
    }

#pragma unroll
    for (int s = 0; s < 2; ++s)
#pragma unroll
      for (int r = 0; r < 16; ++r) sacc[s][r] = exp2_hw(sacc[s][r]);

    uint32_t P2[16];
#pragma unroll
    for (int s = 0; s < 2; ++s)
#pragma unroll
      for (int i = 0; i < 8; ++i)
        asm("v_cvt_pk_bf16_f32 %0, %1, %2"
            : "=v"(P2[s * 8 + i])
            : "v"(sacc[s][2 * i]), "v"(sacc[s][2 * i + 1]));

    __builtin_amdgcn_s_setprio(1);
#pragma unroll
    for (int s = 0; s < 2; ++s) {
#pragma unroll
      for (int u = 0; u < 2; ++u) {
        union { uint32_t uw[4]; bf16x8 v; } pb;
        uint2v ra = __builtin_amdgcn_permlane32_swap(P2[s * 8 + 4 * u],
                                                     P2[s * 8 + 4 * u + 2],
                                                     false, false);
        uint2v rb = __builtin_amdgcn_permlane32_swap(P2[s * 8 + 4 * u + 1],
                                                     P2[s * 8 + 4 * u + 3],
                                                     false, false);
        pb.uw[0] = ra.x;
        pb.uw[1] = rb.x;
        pb.uw[2] = ra.y;
        pb.uw[3] = rb.y;
        const int c = 4 * s + 2 * u + b5;
        sum_acc = __builtin_amdgcn_mfma_f32_32x32x16_bf16(ones.v, pb.v,
                                                          sum_acc, 0, 0, 0);
#pragma unroll
        for (int dt = 0; dt < 4; ++dt) {
          const int rv = dt * 32 + l31;
          const int r2v = rv & 63;
          const int pos = (((rv >> 6) << 3) | c) ^ (r2v & 15);
          bf16x8 vf = *(const bf16x8*)(&sv[cur][r2v * 128 + pos * 8]);
          oacc[dt] = __builtin_amdgcn_mfma_f32_32x32x16_bf16(vf, pb.v, oacc[dt],
                                                             0, 0, 0);
        }
      }
    }
    __builtin_amdgcn_s_setprio(0);
  }

  const float rl = 1.f / sum_acc[0];
  bf16* ob = o + (size_t)(bb * NSEQ + qt * 128 + w * 32 + l31) * DMODEL +
             h * HDIM;
#pragma unroll
  for (int dt = 0; dt < 4; ++dt) {
#pragma unroll
    for (int rg = 0; rg < 4; ++rg) {
      bf16x4 pk4;
#pragma unroll
      for (int e = 0; e < 4; ++e) pk4[e] = (bf16)(oacc[dt][rg * 4 + e] * rl);
      *(bf16x4*)(ob + dt * 32 + rg * 8 + b5 * 4) = pk4;
    }
  }
}

// ---------------------------------------------------------------------------
extern "C" void kernel_launch(void* const* d_in, const int* in_sizes, int n_in,
                              void* d_out, int out_size, void* d_ws,
                              size_t ws_size, hipStream_t stream) {
  (void)in_sizes; (void)n_in; (void)out_size; (void)ws_size;
  const float* x = (const float*)d_in[0];
  const float* freqs = (const float*)d_in[1];
  const float* wq = (const float*)d_in[2];
  const float* bq = (const float*)d_in[3];
  const float* wk = (const float*)d_in[4];
  const float* bk = (const float*)d_in[5];
  const float* wv = (const float*)d_in[6];
  const float* bv = (const float*)d_in[7];
  const float* wo = (const float*)d_in[8];
  const float* bo = (const float*)d_in[9];
  const float* gq = (const float*)d_in[10];
  const float* gk = (const float*)d_in[11];

  char* ws = (char*)d_ws;
  const size_t SZ_TOK = (size_t)MTOT * DMODEL * sizeof(bf16);
  const size_t SZ_W = (size_t)DMODEL * DMODEL * sizeof(bf16);
  bf16* xb = (bf16*)ws;                 // attn-out after qkv
  bf16* qb = (bf16*)(ws + SZ_TOK);
  bf16* kb = (bf16*)(ws + 2 * SZ_TOK);
  bf16* vtb = (bf16*)(ws + 3 * SZ_TOK);
  bf16* wqb = (bf16*)(ws + 4 * SZ_TOK);
  bf16* wkb = (bf16*)(ws + 4 * SZ_TOK + SZ_W);
  bf16* wvb = (bf16*)(ws + 4 * SZ_TOK + 2 * SZ_W);
  bf16* wob = (bf16*)(ws + 4 * SZ_TOK + 3 * SZ_W);

  const int LDSB = 3 * BUFELEMS * (int)sizeof(bf16);  // 147456
  const int LDSQK = 2 * 32768 * (int)sizeof(bf16);    // 131072
  hipFuncSetAttribute((const void*)k_gemm_qk,
                      hipFuncAttributeMaxDynamicSharedMemorySize, LDSQK);
  hipFuncSetAttribute((const void*)k_gemm_v,
                      hipFuncAttributeMaxDynamicSharedMemorySize, LDSB);
  hipFuncSetAttribute((const void*)k_gemm_out,
                      hipFuncAttributeMaxDynamicSharedMemorySize, LDSB);

  k_cvt5<<<2048, 256, 0, stream>>>(x, wq, wk, wv, wo, xb, wqb, wkb, wvb, wob);

  k_gemm_qk<<<256, 512, LDSQK, stream>>>(xb, wqb, wkb, bq, bk, qb, kb);
  k_gemm_v<<<dim3(8, 32), 512, LDSB, stream>>>(xb, wvb, bv, vtb);

  k_norm_rope<<<2048, 256, 0, stream>>>(qb, kb, gq, gk, freqs);

  k_attn<<<512, 256, 0, stream>>>(qb, kb, vtb, xb);

  k_gemm_out<<<dim3(8, 32), 512, LDSB, stream>>>(xb, wob, bo, (float*)d_out);
}